// Round 2
// baseline (2794.724 us; speedup 1.0000x reference)
//
#include <hip/hip_runtime.h>

using ushort = unsigned short;

#define DEVFN static __device__ __forceinline__

constexpr int H = 128;
constexpr int N_AA = 262144, N_CG = 65536;
constexpr int E_CC = 262144, E_CA = 524288;
constexpr int B_GR = 64;

DEVFN float elu(float x) { return x > 0.f ? x : expm1f(x); }

DEVFN float bf2f(ushort s) { return __uint_as_float(((unsigned)s) << 16); }
DEVFN ushort f2bf(float f) {
  unsigned u = __float_as_uint(f);
  return (ushort)((u + 0x7FFFu + ((u >> 16) & 1u)) >> 16);
}

DEVFN void fma4(float4& c, float a, float4 w) {
  c.x += a * w.x; c.y += a * w.y; c.z += a * w.z; c.w += a * w.w;
}

// ---------------- utility kernels ----------------
__global__ void hist_kernel(const int* __restrict__ idx, int n, int* __restrict__ cnt) {
  int i = blockIdx.x * blockDim.x + threadIdx.x;
  int stride = gridDim.x * blockDim.x;
  for (; i < n; i += stride) atomicAdd(&cnt[idx[i]], 1);
}

__global__ void deg_kernel(const int* __restrict__ cnt, int n, float* __restrict__ d) {
  int i = blockIdx.x * blockDim.x + threadIdx.x;
  int stride = gridDim.x * blockDim.x;
  for (; i < n; i += stride) {
    int c = cnt[i]; if (c < 1) c = 1;
    d[i] = rsqrtf((float)c);
  }
}

// exclusive scan: 1024 elems / block (256 thr x int4)
__global__ void scan1_kernel(const int* __restrict__ in, int* __restrict__ out, int* __restrict__ bsum) {
  __shared__ int l[256];
  int tid = threadIdx.x;
  int base = blockIdx.x * 1024 + tid * 4;
  int4 v = *(const int4*)&in[base];
  int s = v.x + v.y + v.z + v.w;
  l[tid] = s; __syncthreads();
  for (int off = 1; off < 256; off <<= 1) {
    int t = (tid >= off) ? l[tid - off] : 0;
    __syncthreads();
    if (tid >= off) l[tid] += t;
    __syncthreads();
  }
  int excl = l[tid] - s;
  if (tid == 255) bsum[blockIdx.x] = l[255];
  int4 o; o.x = excl; o.y = o.x + v.x; o.z = o.y + v.y; o.w = o.z + v.z;
  *(int4*)&out[base] = o;
}

__global__ void scan2_kernel(int* __restrict__ bsum, int nb) {
  __shared__ int l[256];
  int tid = threadIdx.x;
  int v = (tid < nb) ? bsum[tid] : 0;
  l[tid] = v; __syncthreads();
  for (int off = 1; off < 256; off <<= 1) {
    int t = (tid >= off) ? l[tid - off] : 0;
    __syncthreads();
    if (tid >= off) l[tid] += t;
    __syncthreads();
  }
  if (tid < nb) bsum[tid] = l[tid] - v;
}

__global__ void scan3_kernel(int* __restrict__ offs, const int* __restrict__ bsum, int n, int* __restrict__ cur) {
  int i = blockIdx.x * blockDim.x + threadIdx.x;
  int stride = gridDim.x * blockDim.x;
  for (; i < n; i += stride) {
    int o = offs[i] + bsum[i >> 10];
    offs[i] = o; cur[i] = o;
  }
}

__global__ void place_kernel(const int* __restrict__ src, const int* __restrict__ dst, int E,
                             int* __restrict__ cur, int* __restrict__ sorted) {
  int i = blockIdx.x * blockDim.x + threadIdx.x;
  int stride = gridDim.x * blockDim.x;
  for (; i < E; i += stride) {
    int d = dst[i];
    int slot = atomicAdd(&cur[d], 1);
    sorted[slot] = src[i];
  }
}

// ---------------- CSR gather: out[d] = d_in[d] * sum_e d_out[src]*h[src] ----------------
__global__ __launch_bounds__(256) void gather_kernel(
    const ushort* __restrict__ h, const int* __restrict__ sorted_src,
    const int* __restrict__ offs, const int* __restrict__ cnt,
    const float* __restrict__ dout, const float* __restrict__ din,
    ushort* __restrict__ out, int ndst) {
  int lane = threadIdx.x & 31;
  int g0 = (blockIdx.x * blockDim.x + threadIdx.x) >> 5;
  int gstride = (gridDim.x * blockDim.x) >> 5;
  for (int d = g0; d < ndst; d += gstride) {
    int o = offs[d], c = cnt[d];
    float ax = 0.f, ay = 0.f, az = 0.f, aw = 0.f;
    for (int e = o; e < o + c; ++e) {
      int s = sorted_src[e];
      float w = dout[s];
      ushort4 u = *(const ushort4*)&h[(size_t)s * H + lane * 4];
      ax += w * bf2f(u.x); ay += w * bf2f(u.y);
      az += w * bf2f(u.z); aw += w * bf2f(u.w);
    }
    float di = din[d];
    ushort4 r = make_ushort4(f2bf(ax * di), f2bf(ay * di), f2bf(az * di), f2bf(aw * di));
    *(ushort4*)&out[(size_t)d * H + lane * 4] = r;
  }
}

// ---------------- fused GEMM: out = post(A @ W + b) ----------------
// 512 threads, 128-row tiles. Thread (tr,tc): rows tr*8..tr*8+7, cols 4*tc..4*tc+3.
// W [K][128] fp32 in LDS; A tile fp32 in LDS with per-row-group k-rotation swizzle
// (bank-conflict-free reads). ~131 KB static LDS for K=128 -> 1 WG/CU, 2 waves/SIMD.
template<int K, bool ABF, bool ACT, bool SKIP_IN, bool SKIP_BUF, bool LN>
__global__ __launch_bounds__(512) void gemm_fused(
    const void* __restrict__ Av, int ntiles,
    const float* __restrict__ W, const float* __restrict__ bias,
    const float* __restrict__ gamma, const float* __restrict__ beta,
    const ushort* __restrict__ skip, ushort* __restrict__ out) {
  constexpr int AS = K + 4;
  constexpr int KM = K - 1;
  constexpr int F4R = K / 4;
  __shared__ float Wl[K * H];
  __shared__ float Al[128 * AS];
  int tid = threadIdx.x;

  for (int q = tid; q < K * H / 4; q += 512)
    *(float4*)&Wl[q * 4] = *(const float4*)&W[q * 4];

  int tc = tid & 31, tr = tid >> 5;
  const int rot = (4 * tr) & KM;
  const int c = 4 * tc;
  const float* aBase = Al + (tr * 8) * AS;

  for (int tile = blockIdx.x; tile < ntiles; tile += gridDim.x) {
    int r0 = tile * 128;
    __syncthreads();  // prior iter's Al reads done; also orders Wl staging (iter 0 via 2nd sync)
    for (int q = tid; q < 128 * F4R; q += 512) {
      int r = q / F4R, cc = (q % F4R) * 4;
      float4 v;
      if constexpr (ABF) {
        ushort4 u = *(const ushort4*)((const ushort*)Av + (size_t)(r0 + r) * K + cc);
        v.x = bf2f(u.x); v.y = bf2f(u.y); v.z = bf2f(u.z); v.w = bf2f(u.w);
      } else {
        v = *(const float4*)((const float*)Av + (size_t)(r0 + r) * K + cc);
      }
      int rr = (4 * (r >> 3)) & KM;
      *(float4*)&Al[r * AS + ((cc + rr) & KM)] = v;
    }
    __syncthreads();

    float4 acc[8];
#pragma unroll
    for (int i = 0; i < 8; i++) acc[i] = make_float4(0.f, 0.f, 0.f, 0.f);

#pragma unroll 2
    for (int k = 0; k < K; k += 4) {
      int kp = (k + rot) & KM;
      float4 av[8];
#pragma unroll
      for (int r8 = 0; r8 < 8; r8++) av[r8] = *(const float4*)(aBase + r8 * AS + kp);
      float4 w0 = *(const float4*)&Wl[(k + 0) * H + c];
      float4 w1 = *(const float4*)&Wl[(k + 1) * H + c];
      float4 w2 = *(const float4*)&Wl[(k + 2) * H + c];
      float4 w3 = *(const float4*)&Wl[(k + 3) * H + c];
#pragma unroll
      for (int r8 = 0; r8 < 8; r8++) {
        float4 a = av[r8];
        fma4(acc[r8], a.x, w0); fma4(acc[r8], a.y, w1);
        fma4(acc[r8], a.z, w2); fma4(acc[r8], a.w, w3);
      }
    }

    float4 bA = *(const float4*)&bias[c];
    float4 gA, beA;
    if constexpr (LN) {
      gA = *(const float4*)&gamma[c];
      beA = *(const float4*)&beta[c];
    }
#pragma unroll
    for (int r8 = 0; r8 < 8; r8++) {
      int r = tr * 8 + r8;
      size_t grow = (size_t)(r0 + r) * H;
      float4 v;
      v.x = acc[r8].x + bA.x; v.y = acc[r8].y + bA.y;
      v.z = acc[r8].z + bA.z; v.w = acc[r8].w + bA.w;
      if constexpr (ACT) {
        v.x = elu(v.x); v.y = elu(v.y); v.z = elu(v.z); v.w = elu(v.w);
      }
      if constexpr (SKIP_IN) {
        float4 sA = *(const float4*)&Al[r * AS + ((c + rot) & KM)];
        v.x += sA.x; v.y += sA.y; v.z += sA.z; v.w += sA.w;
      }
      if constexpr (SKIP_BUF) {
        ushort4 u = *(const ushort4*)&skip[grow + c];
        v.x += bf2f(u.x); v.y += bf2f(u.y); v.z += bf2f(u.z); v.w += bf2f(u.w);
      }
      if constexpr (LN) {
        float s = v.x + v.y + v.z + v.w;
        s += __shfl_xor(s, 1); s += __shfl_xor(s, 2);
        s += __shfl_xor(s, 4); s += __shfl_xor(s, 8); s += __shfl_xor(s, 16);
        float mu = s * 0.0078125f;
        float t, d;
        t = v.x - mu; d = t * t;  t = v.y - mu; d += t * t;
        t = v.z - mu; d += t * t; t = v.w - mu; d += t * t;
        d += __shfl_xor(d, 1); d += __shfl_xor(d, 2);
        d += __shfl_xor(d, 4); d += __shfl_xor(d, 8); d += __shfl_xor(d, 16);
        float rs = rsqrtf(d * 0.0078125f + 1e-5f);
        v.x = (v.x - mu) * rs * gA.x + beA.x; v.y = (v.y - mu) * rs * gA.y + beA.y;
        v.z = (v.z - mu) * rs * gA.z + beA.z; v.w = (v.w - mu) * rs * gA.w + beA.w;
      }
      *(ushort4*)&out[grow + c] = make_ushort4(f2bf(v.x), f2bf(v.y), f2bf(v.z), f2bf(v.w));
    }
  }
}

// ---------------- pooling ----------------
__global__ __launch_bounds__(128) void pool_sum_kernel(const ushort* __restrict__ h,
                                                       const int* __restrict__ gid,
                                                       float* __restrict__ sums) {
  int f = threadIdx.x;
  int chunk = N_AA / gridDim.x;
  int start = blockIdx.x * chunk, end = start + chunk;
  int g = gid[start];
  float acc = 0.f;
  for (int i = start; i < end; ++i) {
    int gi = gid[i];
    if (gi != g) { atomicAdd(&sums[g * H + f], acc); acc = 0.f; g = gi; }
    acc += bf2f(h[(size_t)i * H + f]);
  }
  atomicAdd(&sums[g * H + f], acc);
}

__global__ void pool_final_kernel(const float* __restrict__ sums, const int* __restrict__ counts,
                                  float* __restrict__ out) {
  int b = blockIdx.x, f = threadIdx.x;
  float c = (float)counts[b];
  out[b * H + f] = sums[b * H + f] / fmaxf(c, 1.f);
  if (f == 0) out[B_GR * H + b] = c;
}

// ---------------- launch helper ----------------
template<int K, bool ABF, bool ACT, bool SKIP_IN, bool SKIP_BUF, bool LN>
static void launch_gemm(const void* A, int nrows, const float* W, const float* bias,
                        const float* gamma, const float* beta, const ushort* skip,
                        ushort* out, hipStream_t stream) {
  int ntiles = nrows / 128;
  gemm_fused<K, ABF, ACT, SKIP_IN, SKIP_BUF, LN><<<ntiles, 512, 0, stream>>>(
      A, ntiles, W, bias, gamma, beta, skip, out);
}

extern "C" void kernel_launch(void* const* d_in, const int* in_sizes, int n_in,
                              void* d_out, int out_size, void* d_ws, size_t ws_size,
                              hipStream_t stream) {
  (void)in_sizes; (void)n_in; (void)out_size; (void)ws_size;
  const float* h_aa0 = (const float*)d_in[0];
  const float* h_cg0 = (const float*)d_in[1];
  const int* src_cc = (const int*)d_in[2];
  const int* dst_cc = (const int*)d_in[3];
  const int* src_ca = (const int*)d_in[4];
  const int* dst_ca = (const int*)d_in[5];
  // d_in[6], d_in[7] (src_ac/dst_ac): dead in the reference — outputs depend only on h_aa
  const int* graph_id = (const int*)d_in[8];
  const float* W_cg0 = (const float*)d_in[9];
  const float* b_cg0 = (const float*)d_in[10];
  const float* g_cg0 = (const float*)d_in[11];
  const float* be_cg0 = (const float*)d_in[12];
  const float* W_aa0 = (const float*)d_in[13];
  const float* b_aa0 = (const float*)d_in[14];
  const float* g_aa0 = (const float*)d_in[15];
  const float* be_aa0 = (const float*)d_in[16];
  const float* W_cc = (const float*)d_in[17];
  const float* b_cc = (const float*)d_in[18];
  const float* W_m1 = (const float*)d_in[19];
  const float* b_m1 = (const float*)d_in[20];
  const float* g_m1 = (const float*)d_in[21];
  const float* be_m1 = (const float*)d_in[22];
  const float* W_ca = (const float*)d_in[23];
  const float* b_ca = (const float*)d_in[24];
  const float* W_m2 = (const float*)d_in[25];
  const float* b_m2 = (const float*)d_in[26];
  const float* g_m2 = (const float*)d_in[27];
  const float* be_m2 = (const float*)d_in[28];
  // d_in[29], d_in[30] (W_ac/b_ac): dead
  const float* W_f = (const float*)d_in[31];
  const float* b_f = (const float*)d_in[32];
  const float* g_f = (const float*)d_in[33];
  const float* be_f = (const float*)d_in[34];

  char* ws = (char*)d_ws;
  size_t off = 0;
  auto alloc = [&](size_t bytes) -> void* {
    void* p = ws + off;
    off = (off + bytes + 255) & ~(size_t)255;
    return p;
  };
  // node-feature buffers in bf16 (storage only; all math fp32)
  ushort* cgA = (ushort*)alloc((size_t)N_CG * H * 2);   // 16 MB
  ushort* G   = (ushort*)alloc((size_t)N_CG * H * 2);   // 16 MB
  ushort* Hb  = (ushort*)alloc((size_t)N_AA * H * 2);   // 64 MB
  ushort* AGG = (ushort*)alloc((size_t)N_AA * H * 2);   // 64 MB
  int* cnt_s_cc = (int*)alloc((size_t)N_CG * 4);  // contiguous block for one memset
  int* cnt_d_cc = (int*)alloc((size_t)N_CG * 4);
  int* cnt_s_ca = (int*)alloc((size_t)N_CG * 4);
  int* cnt_d_ca = (int*)alloc((size_t)N_AA * 4);
  float* dout_cc = (float*)alloc((size_t)N_CG * 4);
  float* din_cc  = (float*)alloc((size_t)N_CG * 4);
  float* dout_ca = (float*)alloc((size_t)N_CG * 4);
  float* din_ca  = (float*)alloc((size_t)N_AA * 4);
  int* offs_cc = (int*)alloc((size_t)N_CG * 4);
  int* cur_cc  = (int*)alloc((size_t)N_CG * 4);
  int* offs_ca = (int*)alloc((size_t)N_AA * 4);
  int* cur_ca  = (int*)alloc((size_t)N_AA * 4);
  int* sorted_cc = (int*)alloc((size_t)E_CC * 4);
  int* sorted_ca = (int*)alloc((size_t)E_CA * 4);
  int* bsumA = (int*)alloc(1024);
  int* bsumB = (int*)alloc(1024);
  float* sums = (float*)alloc((size_t)B_GR * H * 4);  // counts directly after (one memset)
  int* counts = (int*)alloc(256);

  // zero the atomically-accumulated arrays
  hipMemsetAsync(cnt_s_cc, 0, (size_t)(3 * N_CG + N_AA) * 4, stream);
  hipMemsetAsync(sums, 0, (size_t)B_GR * H * 4 + 256, stream);

  // degrees (histograms) + graph counts
  hist_kernel<<<1024, 256, 0, stream>>>(src_cc, E_CC, cnt_s_cc);
  hist_kernel<<<1024, 256, 0, stream>>>(dst_cc, E_CC, cnt_d_cc);
  hist_kernel<<<1024, 256, 0, stream>>>(src_ca, E_CA, cnt_s_ca);
  hist_kernel<<<1024, 256, 0, stream>>>(dst_ca, E_CA, cnt_d_ca);
  hist_kernel<<<1024, 256, 0, stream>>>(graph_id, N_AA, counts);
  deg_kernel<<<256, 256, 0, stream>>>(cnt_s_cc, N_CG, dout_cc);
  deg_kernel<<<256, 256, 0, stream>>>(cnt_d_cc, N_CG, din_cc);
  deg_kernel<<<256, 256, 0, stream>>>(cnt_s_ca, N_CG, dout_ca);
  deg_kernel<<<1024, 256, 0, stream>>>(cnt_d_ca, N_AA, din_ca);

  // CSR by dst: cc
  scan1_kernel<<<N_CG / 1024, 256, 0, stream>>>(cnt_d_cc, offs_cc, bsumA);
  scan2_kernel<<<1, 256, 0, stream>>>(bsumA, N_CG / 1024);
  scan3_kernel<<<256, 256, 0, stream>>>(offs_cc, bsumA, N_CG, cur_cc);
  place_kernel<<<1024, 256, 0, stream>>>(src_cc, dst_cc, E_CC, cur_cc, sorted_cc);
  // CSR by dst: ca
  scan1_kernel<<<N_AA / 1024, 256, 0, stream>>>(cnt_d_ca, offs_ca, bsumB);
  scan2_kernel<<<1, 256, 0, stream>>>(bsumB, N_AA / 1024);
  scan3_kernel<<<256, 256, 0, stream>>>(offs_ca, bsumB, N_AA, cur_ca);
  place_kernel<<<1024, 256, 0, stream>>>(src_ca, dst_ca, E_CA, cur_ca, sorted_ca);

  // input MLPs
  launch_gemm<32, false, true, false, false, true>(h_cg0, N_CG, W_cg0, b_cg0, g_cg0, be_cg0, nullptr, cgA, stream);
  launch_gemm<16, false, true, false, false, true>(h_aa0, N_AA, W_aa0, b_aa0, g_aa0, be_aa0, nullptr, Hb, stream);

  // cg_to_cg conv: gather + GEMM(+ELU) + skip(cgA), in-place on G
  gather_kernel<<<N_CG / 8, 256, 0, stream>>>(cgA, sorted_cc, offs_cc, cnt_d_cc, dout_cc, din_cc, G, N_CG);
  launch_gemm<128, true, true, false, true, false>(G, N_CG, W_cc, b_cc, nullptr, nullptr, cgA, G, stream);

  // m1 on aa (skip + LN), in-place on Hb
  launch_gemm<128, true, true, true, false, true>(Hb, N_AA, W_m1, b_m1, g_m1, be_m1, nullptr, Hb, stream);

  // cg_to_aa conv: gather from G, GEMM(+ELU) + skip(Hb), in-place on AGG
  gather_kernel<<<N_AA / 8, 256, 0, stream>>>(G, sorted_ca, offs_ca, cnt_d_ca, dout_ca, din_ca, AGG, N_AA);
  launch_gemm<128, true, true, false, true, false>(AGG, N_AA, W_ca, b_ca, nullptr, nullptr, Hb, AGG, stream);

  // m2 (skip + LN), in-place
  launch_gemm<128, true, true, true, false, true>(AGG, N_AA, W_m2, b_m2, g_m2, be_m2, nullptr, AGG, stream);

  // final layer (no act, LN), in-place
  launch_gemm<128, true, false, false, false, true>(AGG, N_AA, W_f, b_f, g_f, be_f, nullptr, AGG, stream);

  // mean pool per graph
  pool_sum_kernel<<<1024, 128, 0, stream>>>(AGG, graph_id, sums);
  pool_final_kernel<<<B_GR, 128, 0, stream>>>(sums, counts, (float*)d_out);
}

// Round 3
// 1112.115 us; speedup vs baseline: 2.5130x; 2.5130x over previous
//
#include <hip/hip_runtime.h>

using ushort = unsigned short;

#define DEVFN static __device__ __forceinline__

constexpr int H = 128;
constexpr int N_AA = 262144, N_CG = 65536;
constexpr int E_CC = 262144, E_CA = 524288;
constexpr int B_GR = 64;

DEVFN float elu(float x) { return x > 0.f ? x : expm1f(x); }

DEVFN float bf2f(ushort s) { return __uint_as_float(((unsigned)s) << 16); }
DEVFN ushort f2bf(float f) {
  unsigned u = __float_as_uint(f);
  return (ushort)((u + 0x7FFFu + ((u >> 16) & 1u)) >> 16);
}

DEVFN void fma4(float4& c, float a, float4 w) {
  c.x += a * w.x; c.y += a * w.y; c.z += a * w.z; c.w += a * w.w;
}

// ---------------- utility kernels ----------------
__global__ void hist_kernel(const int* __restrict__ idx, int n, int* __restrict__ cnt) {
  int i = blockIdx.x * blockDim.x + threadIdx.x;
  int stride = gridDim.x * blockDim.x;
  for (; i < n; i += stride) atomicAdd(&cnt[idx[i]], 1);
}

// graph_id is SORTED -> per-graph counts via binary-search boundaries (no atomics)
__global__ void graph_count_kernel(const int* __restrict__ gid, int n, int* __restrict__ counts) {
  int b = threadIdx.x;  // 64 threads, one per graph
  auto lb = [&](int v) {
    int lo = 0, hi = n;
    while (lo < hi) { int m = (lo + hi) >> 1; if (gid[m] < v) lo = m + 1; else hi = m; }
    return lo;
  };
  int s = lb(b), e = lb(b + 1);
  counts[b] = e - s;
}

__global__ void deg_kernel(const int* __restrict__ cnt, int n, float* __restrict__ d) {
  int i = blockIdx.x * blockDim.x + threadIdx.x;
  int stride = gridDim.x * blockDim.x;
  for (; i < n; i += stride) {
    int c = cnt[i]; if (c < 1) c = 1;
    d[i] = rsqrtf((float)c);
  }
}

// exclusive scan: 1024 elems / block (256 thr x int4)
__global__ void scan1_kernel(const int* __restrict__ in, int* __restrict__ out, int* __restrict__ bsum) {
  __shared__ int l[256];
  int tid = threadIdx.x;
  int base = blockIdx.x * 1024 + tid * 4;
  int4 v = *(const int4*)&in[base];
  int s = v.x + v.y + v.z + v.w;
  l[tid] = s; __syncthreads();
  for (int off = 1; off < 256; off <<= 1) {
    int t = (tid >= off) ? l[tid - off] : 0;
    __syncthreads();
    if (tid >= off) l[tid] += t;
    __syncthreads();
  }
  int excl = l[tid] - s;
  if (tid == 255) bsum[blockIdx.x] = l[255];
  int4 o; o.x = excl; o.y = o.x + v.x; o.z = o.y + v.y; o.w = o.z + v.z;
  *(int4*)&out[base] = o;
}

__global__ void scan2_kernel(int* __restrict__ bsum, int nb) {
  __shared__ int l[256];
  int tid = threadIdx.x;
  int v = (tid < nb) ? bsum[tid] : 0;
  l[tid] = v; __syncthreads();
  for (int off = 1; off < 256; off <<= 1) {
    int t = (tid >= off) ? l[tid - off] : 0;
    __syncthreads();
    if (tid >= off) l[tid] += t;
    __syncthreads();
  }
  if (tid < nb) bsum[tid] = l[tid] - v;
}

__global__ void scan3_kernel(int* __restrict__ offs, const int* __restrict__ bsum, int n, int* __restrict__ cur) {
  int i = blockIdx.x * blockDim.x + threadIdx.x;
  int stride = gridDim.x * blockDim.x;
  for (; i < n; i += stride) {
    int o = offs[i] + bsum[i >> 10];
    offs[i] = o; cur[i] = o;
  }
}

__global__ void place_kernel(const int* __restrict__ src, const int* __restrict__ dst, int E,
                             int* __restrict__ cur, int* __restrict__ sorted) {
  int i = blockIdx.x * blockDim.x + threadIdx.x;
  int stride = gridDim.x * blockDim.x;
  for (; i < E; i += stride) {
    int d = dst[i];
    int slot = atomicAdd(&cur[d], 1);
    sorted[slot] = src[i];
  }
}

// ---------------- CSR gather: out[d] = d_in[d] * sum_e d_out[src]*h[src] ----------------
__global__ __launch_bounds__(256) void gather_kernel(
    const ushort* __restrict__ h, const int* __restrict__ sorted_src,
    const int* __restrict__ offs, const int* __restrict__ cnt,
    const float* __restrict__ dout, const float* __restrict__ din,
    ushort* __restrict__ out, int ndst) {
  int lane = threadIdx.x & 31;
  int g0 = (blockIdx.x * blockDim.x + threadIdx.x) >> 5;
  int gstride = (gridDim.x * blockDim.x) >> 5;
  for (int d = g0; d < ndst; d += gstride) {
    int o = offs[d], c = cnt[d];
    float ax = 0.f, ay = 0.f, az = 0.f, aw = 0.f;
    for (int e = o; e < o + c; ++e) {
      int s = sorted_src[e];
      float w = dout[s];
      ushort4 u = *(const ushort4*)&h[(size_t)s * H + lane * 4];
      ax += w * bf2f(u.x); ay += w * bf2f(u.y);
      az += w * bf2f(u.z); aw += w * bf2f(u.w);
    }
    float di = din[d];
    ushort4 r = make_ushort4(f2bf(ax * di), f2bf(ay * di), f2bf(az * di), f2bf(aw * di));
    *(ushort4*)&out[(size_t)d * H + lane * 4] = r;
  }
}

// ---------------- fused GEMM: out = post(A @ W + b) ----------------
// 512 threads, 128-row tiles. Thread (tr,tc): rows tr*8..tr*8+7, cols 4*tc..4*tc+3.
// W [K][128] fp32 in LDS; A tile fp32 in LDS with per-row-group k-rotation swizzle
// (bank-conflict-free reads). ~131 KB static LDS for K=128 -> 1 WG/CU, 2 waves/SIMD.
template<int K, bool ABF, bool ACT, bool SKIP_IN, bool SKIP_BUF, bool LN>
__global__ __launch_bounds__(512) void gemm_fused(
    const void* __restrict__ Av, int ntiles,
    const float* __restrict__ W, const float* __restrict__ bias,
    const float* __restrict__ gamma, const float* __restrict__ beta,
    const ushort* __restrict__ skip, ushort* __restrict__ out) {
  constexpr int AS = K + 4;
  constexpr int KM = K - 1;
  constexpr int F4R = K / 4;
  __shared__ float Wl[K * H];
  __shared__ float Al[128 * AS];
  int tid = threadIdx.x;

  for (int q = tid; q < K * H / 4; q += 512)
    *(float4*)&Wl[q * 4] = *(const float4*)&W[q * 4];

  int tc = tid & 31, tr = tid >> 5;
  const int rot = (4 * tr) & KM;
  const int c = 4 * tc;
  const float* aBase = Al + (tr * 8) * AS;

  for (int tile = blockIdx.x; tile < ntiles; tile += gridDim.x) {
    int r0 = tile * 128;
    __syncthreads();  // prior iter's Al reads done; also orders Wl staging (iter 0 via 2nd sync)
    for (int q = tid; q < 128 * F4R; q += 512) {
      int r = q / F4R, cc = (q % F4R) * 4;
      float4 v;
      if constexpr (ABF) {
        ushort4 u = *(const ushort4*)((const ushort*)Av + (size_t)(r0 + r) * K + cc);
        v.x = bf2f(u.x); v.y = bf2f(u.y); v.z = bf2f(u.z); v.w = bf2f(u.w);
      } else {
        v = *(const float4*)((const float*)Av + (size_t)(r0 + r) * K + cc);
      }
      int rr = (4 * (r >> 3)) & KM;
      *(float4*)&Al[r * AS + ((cc + rr) & KM)] = v;
    }
    __syncthreads();

    float4 acc[8];
#pragma unroll
    for (int i = 0; i < 8; i++) acc[i] = make_float4(0.f, 0.f, 0.f, 0.f);

#pragma unroll 2
    for (int k = 0; k < K; k += 4) {
      int kp = (k + rot) & KM;
      float4 av[8];
#pragma unroll
      for (int r8 = 0; r8 < 8; r8++) av[r8] = *(const float4*)(aBase + r8 * AS + kp);
      float4 w0 = *(const float4*)&Wl[(k + 0) * H + c];
      float4 w1 = *(const float4*)&Wl[(k + 1) * H + c];
      float4 w2 = *(const float4*)&Wl[(k + 2) * H + c];
      float4 w3 = *(const float4*)&Wl[(k + 3) * H + c];
#pragma unroll
      for (int r8 = 0; r8 < 8; r8++) {
        float4 a = av[r8];
        fma4(acc[r8], a.x, w0); fma4(acc[r8], a.y, w1);
        fma4(acc[r8], a.z, w2); fma4(acc[r8], a.w, w3);
      }
    }

    float4 bA = *(const float4*)&bias[c];
    float4 gA, beA;
    if constexpr (LN) {
      gA = *(const float4*)&gamma[c];
      beA = *(const float4*)&beta[c];
    }
#pragma unroll
    for (int r8 = 0; r8 < 8; r8++) {
      int r = tr * 8 + r8;
      size_t grow = (size_t)(r0 + r) * H;
      float4 v;
      v.x = acc[r8].x + bA.x; v.y = acc[r8].y + bA.y;
      v.z = acc[r8].z + bA.z; v.w = acc[r8].w + bA.w;
      if constexpr (ACT) {
        v.x = elu(v.x); v.y = elu(v.y); v.z = elu(v.z); v.w = elu(v.w);
      }
      if constexpr (SKIP_IN) {
        float4 sA = *(const float4*)&Al[r * AS + ((c + rot) & KM)];
        v.x += sA.x; v.y += sA.y; v.z += sA.z; v.w += sA.w;
      }
      if constexpr (SKIP_BUF) {
        ushort4 u = *(const ushort4*)&skip[grow + c];
        v.x += bf2f(u.x); v.y += bf2f(u.y); v.z += bf2f(u.z); v.w += bf2f(u.w);
      }
      if constexpr (LN) {
        float s = v.x + v.y + v.z + v.w;
        s += __shfl_xor(s, 1); s += __shfl_xor(s, 2);
        s += __shfl_xor(s, 4); s += __shfl_xor(s, 8); s += __shfl_xor(s, 16);
        float mu = s * 0.0078125f;
        float t, d;
        t = v.x - mu; d = t * t;  t = v.y - mu; d += t * t;
        t = v.z - mu; d += t * t; t = v.w - mu; d += t * t;
        d += __shfl_xor(d, 1); d += __shfl_xor(d, 2);
        d += __shfl_xor(d, 4); d += __shfl_xor(d, 8); d += __shfl_xor(d, 16);
        float rs = rsqrtf(d * 0.0078125f + 1e-5f);
        v.x = (v.x - mu) * rs * gA.x + beA.x; v.y = (v.y - mu) * rs * gA.y + beA.y;
        v.z = (v.z - mu) * rs * gA.z + beA.z; v.w = (v.w - mu) * rs * gA.w + beA.w;
      }
      *(ushort4*)&out[grow + c] = make_ushort4(f2bf(v.x), f2bf(v.y), f2bf(v.z), f2bf(v.w));
    }
  }
}

// ---------------- pooling ----------------
__global__ __launch_bounds__(128) void pool_sum_kernel(const ushort* __restrict__ h,
                                                       const int* __restrict__ gid,
                                                       float* __restrict__ sums) {
  int f = threadIdx.x;
  int chunk = N_AA / gridDim.x;
  int start = blockIdx.x * chunk, end = start + chunk;
  int g = gid[start];
  float acc = 0.f;
  for (int i = start; i < end; ++i) {
    int gi = gid[i];
    if (gi != g) { atomicAdd(&sums[g * H + f], acc); acc = 0.f; g = gi; }
    acc += bf2f(h[(size_t)i * H + f]);
  }
  atomicAdd(&sums[g * H + f], acc);
}

__global__ void pool_final_kernel(const float* __restrict__ sums, const int* __restrict__ counts,
                                  float* __restrict__ out) {
  int b = blockIdx.x, f = threadIdx.x;
  float c = (float)counts[b];
  out[b * H + f] = sums[b * H + f] / fmaxf(c, 1.f);
  if (f == 0) out[B_GR * H + b] = c;
}

// ---------------- launch helper ----------------
template<int K, bool ABF, bool ACT, bool SKIP_IN, bool SKIP_BUF, bool LN>
static void launch_gemm(const void* A, int nrows, const float* W, const float* bias,
                        const float* gamma, const float* beta, const ushort* skip,
                        ushort* out, hipStream_t stream) {
  int ntiles = nrows / 128;
  gemm_fused<K, ABF, ACT, SKIP_IN, SKIP_BUF, LN><<<ntiles, 512, 0, stream>>>(
      A, ntiles, W, bias, gamma, beta, skip, out);
}

extern "C" void kernel_launch(void* const* d_in, const int* in_sizes, int n_in,
                              void* d_out, int out_size, void* d_ws, size_t ws_size,
                              hipStream_t stream) {
  (void)in_sizes; (void)n_in; (void)out_size; (void)ws_size;
  const float* h_aa0 = (const float*)d_in[0];
  const float* h_cg0 = (const float*)d_in[1];
  const int* src_cc = (const int*)d_in[2];
  const int* dst_cc = (const int*)d_in[3];
  const int* src_ca = (const int*)d_in[4];
  const int* dst_ca = (const int*)d_in[5];
  // d_in[6], d_in[7] (src_ac/dst_ac): dead in the reference — outputs depend only on h_aa
  const int* graph_id = (const int*)d_in[8];
  const float* W_cg0 = (const float*)d_in[9];
  const float* b_cg0 = (const float*)d_in[10];
  const float* g_cg0 = (const float*)d_in[11];
  const float* be_cg0 = (const float*)d_in[12];
  const float* W_aa0 = (const float*)d_in[13];
  const float* b_aa0 = (const float*)d_in[14];
  const float* g_aa0 = (const float*)d_in[15];
  const float* be_aa0 = (const float*)d_in[16];
  const float* W_cc = (const float*)d_in[17];
  const float* b_cc = (const float*)d_in[18];
  const float* W_m1 = (const float*)d_in[19];
  const float* b_m1 = (const float*)d_in[20];
  const float* g_m1 = (const float*)d_in[21];
  const float* be_m1 = (const float*)d_in[22];
  const float* W_ca = (const float*)d_in[23];
  const float* b_ca = (const float*)d_in[24];
  const float* W_m2 = (const float*)d_in[25];
  const float* b_m2 = (const float*)d_in[26];
  const float* g_m2 = (const float*)d_in[27];
  const float* be_m2 = (const float*)d_in[28];
  // d_in[29], d_in[30] (W_ac/b_ac): dead
  const float* W_f = (const float*)d_in[31];
  const float* b_f = (const float*)d_in[32];
  const float* g_f = (const float*)d_in[33];
  const float* be_f = (const float*)d_in[34];

  char* ws = (char*)d_ws;
  size_t off = 0;
  auto alloc = [&](size_t bytes) -> void* {
    void* p = ws + off;
    off = (off + bytes + 255) & ~(size_t)255;
    return p;
  };
  // node-feature buffers in bf16 (storage only; all math fp32)
  ushort* cgA = (ushort*)alloc((size_t)N_CG * H * 2);   // 16 MB
  ushort* G   = (ushort*)alloc((size_t)N_CG * H * 2);   // 16 MB
  ushort* Hb  = (ushort*)alloc((size_t)N_AA * H * 2);   // 64 MB
  ushort* AGG = (ushort*)alloc((size_t)N_AA * H * 2);   // 64 MB
  int* cnt_s_cc = (int*)alloc((size_t)N_CG * 4);  // contiguous block for one memset
  int* cnt_d_cc = (int*)alloc((size_t)N_CG * 4);
  int* cnt_s_ca = (int*)alloc((size_t)N_CG * 4);
  int* cnt_d_ca = (int*)alloc((size_t)N_AA * 4);
  float* dout_cc = (float*)alloc((size_t)N_CG * 4);
  float* din_cc  = (float*)alloc((size_t)N_CG * 4);
  float* dout_ca = (float*)alloc((size_t)N_CG * 4);
  float* din_ca  = (float*)alloc((size_t)N_AA * 4);
  int* offs_cc = (int*)alloc((size_t)N_CG * 4);
  int* cur_cc  = (int*)alloc((size_t)N_CG * 4);
  int* offs_ca = (int*)alloc((size_t)N_AA * 4);
  int* cur_ca  = (int*)alloc((size_t)N_AA * 4);
  int* sorted_cc = (int*)alloc((size_t)E_CC * 4);
  int* sorted_ca = (int*)alloc((size_t)E_CA * 4);
  int* bsumA = (int*)alloc(1024);
  int* bsumB = (int*)alloc(1024);
  float* sums = (float*)alloc((size_t)B_GR * H * 4);
  int* counts = (int*)alloc(256);

  // zero the atomically-accumulated arrays
  hipMemsetAsync(cnt_s_cc, 0, (size_t)(3 * N_CG + N_AA) * 4, stream);
  hipMemsetAsync(sums, 0, (size_t)B_GR * H * 4, stream);

  // degrees (edge histograms) + per-graph counts (binary search over sorted graph_id)
  hist_kernel<<<1024, 256, 0, stream>>>(src_cc, E_CC, cnt_s_cc);
  hist_kernel<<<1024, 256, 0, stream>>>(dst_cc, E_CC, cnt_d_cc);
  hist_kernel<<<1024, 256, 0, stream>>>(src_ca, E_CA, cnt_s_ca);
  hist_kernel<<<1024, 256, 0, stream>>>(dst_ca, E_CA, cnt_d_ca);
  graph_count_kernel<<<1, 64, 0, stream>>>(graph_id, N_AA, counts);
  deg_kernel<<<256, 256, 0, stream>>>(cnt_s_cc, N_CG, dout_cc);
  deg_kernel<<<256, 256, 0, stream>>>(cnt_d_cc, N_CG, din_cc);
  deg_kernel<<<256, 256, 0, stream>>>(cnt_s_ca, N_CG, dout_ca);
  deg_kernel<<<1024, 256, 0, stream>>>(cnt_d_ca, N_AA, din_ca);

  // CSR by dst: cc
  scan1_kernel<<<N_CG / 1024, 256, 0, stream>>>(cnt_d_cc, offs_cc, bsumA);
  scan2_kernel<<<1, 256, 0, stream>>>(bsumA, N_CG / 1024);
  scan3_kernel<<<256, 256, 0, stream>>>(offs_cc, bsumA, N_CG, cur_cc);
  place_kernel<<<1024, 256, 0, stream>>>(src_cc, dst_cc, E_CC, cur_cc, sorted_cc);
  // CSR by dst: ca
  scan1_kernel<<<N_AA / 1024, 256, 0, stream>>>(cnt_d_ca, offs_ca, bsumB);
  scan2_kernel<<<1, 256, 0, stream>>>(bsumB, N_AA / 1024);
  scan3_kernel<<<256, 256, 0, stream>>>(offs_ca, bsumB, N_AA, cur_ca);
  place_kernel<<<1024, 256, 0, stream>>>(src_ca, dst_ca, E_CA, cur_ca, sorted_ca);

  // input MLPs
  launch_gemm<32, false, true, false, false, true>(h_cg0, N_CG, W_cg0, b_cg0, g_cg0, be_cg0, nullptr, cgA, stream);
  launch_gemm<16, false, true, false, false, true>(h_aa0, N_AA, W_aa0, b_aa0, g_aa0, be_aa0, nullptr, Hb, stream);

  // cg_to_cg conv: gather + GEMM(+ELU) + skip(cgA), in-place on G
  gather_kernel<<<N_CG / 8, 256, 0, stream>>>(cgA, sorted_cc, offs_cc, cnt_d_cc, dout_cc, din_cc, G, N_CG);
  launch_gemm<128, true, true, false, true, false>(G, N_CG, W_cc, b_cc, nullptr, nullptr, cgA, G, stream);

  // m1 on aa (skip + LN), in-place on Hb
  launch_gemm<128, true, true, true, false, true>(Hb, N_AA, W_m1, b_m1, g_m1, be_m1, nullptr, Hb, stream);

  // cg_to_aa conv: gather from G, GEMM(+ELU) + skip(Hb), in-place on AGG
  gather_kernel<<<N_AA / 8, 256, 0, stream>>>(G, sorted_ca, offs_ca, cnt_d_ca, dout_ca, din_ca, AGG, N_AA);
  launch_gemm<128, true, true, false, true, false>(AGG, N_AA, W_ca, b_ca, nullptr, nullptr, Hb, AGG, stream);

  // m2 (skip + LN), in-place
  launch_gemm<128, true, true, true, false, true>(AGG, N_AA, W_m2, b_m2, g_m2, be_m2, nullptr, AGG, stream);

  // final layer (no act, LN), in-place
  launch_gemm<128, true, false, false, false, true>(AGG, N_AA, W_f, b_f, g_f, be_f, nullptr, AGG, stream);

  // mean pool per graph
  pool_sum_kernel<<<1024, 128, 0, stream>>>(AGG, graph_id, sums);
  pool_final_kernel<<<B_GR, 128, 0, stream>>>(sums, counts, (float*)d_out);
}

// Round 4
// 736.204 us; speedup vs baseline: 3.7961x; 1.5106x over previous
//
#include <hip/hip_runtime.h>

using ushort = unsigned short;

#define DEVFN static __device__ __forceinline__

constexpr int H = 128;
constexpr int N_AA = 262144, N_CG = 65536;
constexpr int E_CC = 262144, E_CA = 524288;
constexpr int B_GR = 64;

typedef __attribute__((ext_vector_type(8))) short bf16x8;
typedef __attribute__((ext_vector_type(4))) float f32x4;

DEVFN float elu(float x) { return x > 0.f ? x : expm1f(x); }

DEVFN float bf2f(ushort s) { return __uint_as_float(((unsigned)s) << 16); }
DEVFN ushort f2bf(float f) {
  unsigned u = __float_as_uint(f);
  return (ushort)((u + 0x7FFFu + ((u >> 16) & 1u)) >> 16);
}

DEVFN void fma4(float4& c, float a, float4 w) {
  c.x += a * w.x; c.y += a * w.y; c.z += a * w.z; c.w += a * w.w;
}

// ---------------- utility kernels ----------------
__global__ void hist_kernel(const int* __restrict__ idx, int n, int* __restrict__ cnt) {
  int i = blockIdx.x * blockDim.x + threadIdx.x;
  int stride = gridDim.x * blockDim.x;
  for (; i < n; i += stride) atomicAdd(&cnt[idx[i]], 1);
}

// graph_id is SORTED -> per-graph counts via binary-search boundaries (no atomics)
__global__ void graph_count_kernel(const int* __restrict__ gid, int n, int* __restrict__ counts) {
  int b = threadIdx.x;  // 64 threads, one per graph
  auto lb = [&](int v) {
    int lo = 0, hi = n;
    while (lo < hi) { int m = (lo + hi) >> 1; if (gid[m] < v) lo = m + 1; else hi = m; }
    return lo;
  };
  int s = lb(b), e = lb(b + 1);
  counts[b] = e - s;
}

__global__ void deg_kernel(const int* __restrict__ cnt, int n, float* __restrict__ d) {
  int i = blockIdx.x * blockDim.x + threadIdx.x;
  int stride = gridDim.x * blockDim.x;
  for (; i < n; i += stride) {
    int c = cnt[i]; if (c < 1) c = 1;
    d[i] = rsqrtf((float)c);
  }
}

// transpose W [128][128] fp32 (W[k][n]) -> Wt [128][128] bf16 (Wt[n][k])
__global__ void transpose_w_kernel(const float* __restrict__ W, ushort* __restrict__ Wt) {
  int idx = blockIdx.x * 256 + threadIdx.x;  // grid 64 x 256 = 16384
  int n = idx >> 7, k = idx & 127;
  Wt[idx] = f2bf(W[k * 128 + n]);
}

// exclusive scan: 1024 elems / block (256 thr x int4)
__global__ void scan1_kernel(const int* __restrict__ in, int* __restrict__ out, int* __restrict__ bsum) {
  __shared__ int l[256];
  int tid = threadIdx.x;
  int base = blockIdx.x * 1024 + tid * 4;
  int4 v = *(const int4*)&in[base];
  int s = v.x + v.y + v.z + v.w;
  l[tid] = s; __syncthreads();
  for (int off = 1; off < 256; off <<= 1) {
    int t = (tid >= off) ? l[tid - off] : 0;
    __syncthreads();
    if (tid >= off) l[tid] += t;
    __syncthreads();
  }
  int excl = l[tid] - s;
  if (tid == 255) bsum[blockIdx.x] = l[255];
  int4 o; o.x = excl; o.y = o.x + v.x; o.z = o.y + v.y; o.w = o.z + v.z;
  *(int4*)&out[base] = o;
}

__global__ void scan2_kernel(int* __restrict__ bsum, int nb) {
  __shared__ int l[256];
  int tid = threadIdx.x;
  int v = (tid < nb) ? bsum[tid] : 0;
  l[tid] = v; __syncthreads();
  for (int off = 1; off < 256; off <<= 1) {
    int t = (tid >= off) ? l[tid - off] : 0;
    __syncthreads();
    if (tid >= off) l[tid] += t;
    __syncthreads();
  }
  if (tid < nb) bsum[tid] = l[tid] - v;
}

__global__ void scan3_kernel(int* __restrict__ offs, const int* __restrict__ bsum, int n, int* __restrict__ cur) {
  int i = blockIdx.x * blockDim.x + threadIdx.x;
  int stride = gridDim.x * blockDim.x;
  for (; i < n; i += stride) {
    int o = offs[i] + bsum[i >> 10];
    offs[i] = o; cur[i] = o;
  }
}

__global__ void place_kernel(const int* __restrict__ src, const int* __restrict__ dst, int E,
                             int* __restrict__ cur, int* __restrict__ sorted) {
  int i = blockIdx.x * blockDim.x + threadIdx.x;
  int stride = gridDim.x * blockDim.x;
  for (; i < E; i += stride) {
    int d = dst[i];
    int slot = atomicAdd(&cur[d], 1);
    sorted[slot] = src[i];
  }
}

// ---------------- CSR gather: out[d] = d_in[d] * sum_e d_out[src]*h[src] ----------------
__global__ __launch_bounds__(256) void gather_kernel(
    const ushort* __restrict__ h, const int* __restrict__ sorted_src,
    const int* __restrict__ offs, const int* __restrict__ cnt,
    const float* __restrict__ dout, const float* __restrict__ din,
    ushort* __restrict__ out, int ndst) {
  int lane = threadIdx.x & 31;
  int g0 = (blockIdx.x * blockDim.x + threadIdx.x) >> 5;
  int gstride = (gridDim.x * blockDim.x) >> 5;
  for (int d = g0; d < ndst; d += gstride) {
    int o = offs[d], c = cnt[d];
    float ax = 0.f, ay = 0.f, az = 0.f, aw = 0.f;
    for (int e = o; e < o + c; ++e) {
      int s = sorted_src[e];
      float w = dout[s];
      ushort4 u = *(const ushort4*)&h[(size_t)s * H + lane * 4];
      ax += w * bf2f(u.x); ay += w * bf2f(u.y);
      az += w * bf2f(u.z); aw += w * bf2f(u.w);
    }
    float di = din[d];
    ushort4 r = make_ushort4(f2bf(ax * di), f2bf(ay * di), f2bf(az * di), f2bf(aw * di));
    *(ushort4*)&out[(size_t)d * H + lane * 4] = r;
  }
}

// ---------------- MFMA GEMM (K=128): out = post(A @ W + b) ----------------
// Transposed orientation: D = Wt_frag x Anode_frag via mfma_f32_16x16x32_bf16.
// D layout: col(lane&15) = node, row(lane>>4)*4+reg = 4 CONSECUTIVE features ->
// packed 8B stores, LN = 2 shfl_xor. W^T fragments hoisted fully to registers
// (128 VGPR), zero LDS, zero syncthreads. Each wave: 16 nodes per group iter.
template<bool ACT, bool SKIP, bool LN>
__global__ __launch_bounds__(256) void gemm_mfma(
    const ushort* __restrict__ A, int ngrp,
    const ushort* __restrict__ Wt,  // [n][k] bf16
    const float* __restrict__ bias,
    const float* __restrict__ gamma, const float* __restrict__ beta,
    const ushort* __restrict__ skip, ushort* __restrict__ out) {
  int lane = threadIdx.x & 63;
  int wave = threadIdx.x >> 6;
  int t = lane & 15, q = lane >> 4;

  // hoist W^T fragments: wf[ks][nf] -> lane holds Wt[nf*16+t][ks*32+q*8 .. +8)
  bf16x8 wf[4][8];
#pragma unroll
  for (int ks = 0; ks < 4; ks++)
#pragma unroll
    for (int nf = 0; nf < 8; nf++)
      wf[ks][nf] = *(const bf16x8*)(Wt + (nf * 16 + t) * 128 + ks * 32 + q * 8);

  for (int grp = blockIdx.x; grp < ngrp; grp += gridDim.x) {
    int m0 = grp * 64 + wave * 16;
    size_t mrow = (size_t)(m0 + t) * H;
    const ushort* arow = A + mrow + q * 8;

    bf16x8 bfr[4];
#pragma unroll
    for (int ks = 0; ks < 4; ks++) bfr[ks] = *(const bf16x8*)(arow + ks * 32);

    f32x4 acc[8];
#pragma unroll
    for (int nf = 0; nf < 8; nf++) acc[nf] = (f32x4){0.f, 0.f, 0.f, 0.f};
#pragma unroll
    for (int ks = 0; ks < 4; ks++)
#pragma unroll
      for (int nf = 0; nf < 8; nf++)
        acc[nf] = __builtin_amdgcn_mfma_f32_16x16x32_bf16(wf[ks][nf], bfr[ks], acc[nf], 0, 0, 0);

    // epilogue: this lane owns node m0+t, features n = nf*16 + q*4 + {0..3}
#pragma unroll
    for (int nf = 0; nf < 8; nf++) {
      float4 bb = *(const float4*)&bias[nf * 16 + q * 4];
      acc[nf][0] += bb.x; acc[nf][1] += bb.y; acc[nf][2] += bb.z; acc[nf][3] += bb.w;
      if constexpr (ACT) {
        acc[nf][0] = elu(acc[nf][0]); acc[nf][1] = elu(acc[nf][1]);
        acc[nf][2] = elu(acc[nf][2]); acc[nf][3] = elu(acc[nf][3]);
      }
      if constexpr (SKIP) {
        ushort4 u = *(const ushort4*)&skip[mrow + nf * 16 + q * 4];
        acc[nf][0] += bf2f(u.x); acc[nf][1] += bf2f(u.y);
        acc[nf][2] += bf2f(u.z); acc[nf][3] += bf2f(u.w);
      }
    }
    if constexpr (LN) {
      float s = 0.f;
#pragma unroll
      for (int nf = 0; nf < 8; nf++)
        s += acc[nf][0] + acc[nf][1] + acc[nf][2] + acc[nf][3];
      s += __shfl_xor(s, 16); s += __shfl_xor(s, 32);
      float mu = s * 0.0078125f;
      float d = 0.f;
#pragma unroll
      for (int nf = 0; nf < 8; nf++) {
        float x;
        x = acc[nf][0] - mu; d += x * x; x = acc[nf][1] - mu; d += x * x;
        x = acc[nf][2] - mu; d += x * x; x = acc[nf][3] - mu; d += x * x;
      }
      d += __shfl_xor(d, 16); d += __shfl_xor(d, 32);
      float rs = rsqrtf(d * 0.0078125f + 1e-5f);
#pragma unroll
      for (int nf = 0; nf < 8; nf++) {
        float4 gg = *(const float4*)&gamma[nf * 16 + q * 4];
        float4 be = *(const float4*)&beta[nf * 16 + q * 4];
        acc[nf][0] = (acc[nf][0] - mu) * rs * gg.x + be.x;
        acc[nf][1] = (acc[nf][1] - mu) * rs * gg.y + be.y;
        acc[nf][2] = (acc[nf][2] - mu) * rs * gg.z + be.z;
        acc[nf][3] = (acc[nf][3] - mu) * rs * gg.w + be.w;
      }
    }
#pragma unroll
    for (int nf = 0; nf < 8; nf++) {
      *(ushort4*)&out[mrow + nf * 16 + q * 4] = make_ushort4(
          f2bf(acc[nf][0]), f2bf(acc[nf][1]), f2bf(acc[nf][2]), f2bf(acc[nf][3]));
    }
  }
}

// ---------------- VALU GEMM for small-K input MLPs ----------------
template<int K, bool ACT, bool SKIP_IN, bool SKIP_BUF, bool LN>
__global__ __launch_bounds__(512) void gemm_fused(
    const void* __restrict__ Av, int ntiles,
    const float* __restrict__ W, const float* __restrict__ bias,
    const float* __restrict__ gamma, const float* __restrict__ beta,
    const ushort* __restrict__ skip, ushort* __restrict__ out) {
  constexpr int AS = K + 4;
  constexpr int KM = K - 1;
  constexpr int F4R = K / 4;
  __shared__ float Wl[K * H];
  __shared__ float Al[128 * AS];
  int tid = threadIdx.x;

  for (int q = tid; q < K * H / 4; q += 512)
    *(float4*)&Wl[q * 4] = *(const float4*)&W[q * 4];

  int tc = tid & 31, tr = tid >> 5;
  const int rot = (4 * tr) & KM;
  const int c = 4 * tc;
  const float* aBase = Al + (tr * 8) * AS;

  for (int tile = blockIdx.x; tile < ntiles; tile += gridDim.x) {
    int r0 = tile * 128;
    __syncthreads();
    for (int q = tid; q < 128 * F4R; q += 512) {
      int r = q / F4R, cc = (q % F4R) * 4;
      float4 v = *(const float4*)((const float*)Av + (size_t)(r0 + r) * K + cc);
      int rr = (4 * (r >> 3)) & KM;
      *(float4*)&Al[r * AS + ((cc + rr) & KM)] = v;
    }
    __syncthreads();

    float4 acc[8];
#pragma unroll
    for (int i = 0; i < 8; i++) acc[i] = make_float4(0.f, 0.f, 0.f, 0.f);

#pragma unroll 2
    for (int k = 0; k < K; k += 4) {
      int kp = (k + rot) & KM;
      float4 av[8];
#pragma unroll
      for (int r8 = 0; r8 < 8; r8++) av[r8] = *(const float4*)(aBase + r8 * AS + kp);
      float4 w0 = *(const float4*)&Wl[(k + 0) * H + c];
      float4 w1 = *(const float4*)&Wl[(k + 1) * H + c];
      float4 w2 = *(const float4*)&Wl[(k + 2) * H + c];
      float4 w3 = *(const float4*)&Wl[(k + 3) * H + c];
#pragma unroll
      for (int r8 = 0; r8 < 8; r8++) {
        float4 a = av[r8];
        fma4(acc[r8], a.x, w0); fma4(acc[r8], a.y, w1);
        fma4(acc[r8], a.z, w2); fma4(acc[r8], a.w, w3);
      }
    }

    float4 bA = *(const float4*)&bias[c];
    float4 gA, beA;
    if constexpr (LN) {
      gA = *(const float4*)&gamma[c];
      beA = *(const float4*)&beta[c];
    }
#pragma unroll
    for (int r8 = 0; r8 < 8; r8++) {
      int r = tr * 8 + r8;
      size_t grow = (size_t)(r0 + r) * H;
      float4 v;
      v.x = acc[r8].x + bA.x; v.y = acc[r8].y + bA.y;
      v.z = acc[r8].z + bA.z; v.w = acc[r8].w + bA.w;
      if constexpr (ACT) {
        v.x = elu(v.x); v.y = elu(v.y); v.z = elu(v.z); v.w = elu(v.w);
      }
      if constexpr (SKIP_IN) {
        float4 sA = *(const float4*)&Al[r * AS + ((c + rot) & KM)];
        v.x += sA.x; v.y += sA.y; v.z += sA.z; v.w += sA.w;
      }
      if constexpr (SKIP_BUF) {
        ushort4 u = *(const ushort4*)&skip[grow + c];
        v.x += bf2f(u.x); v.y += bf2f(u.y); v.z += bf2f(u.z); v.w += bf2f(u.w);
      }
      if constexpr (LN) {
        float s = v.x + v.y + v.z + v.w;
        s += __shfl_xor(s, 1); s += __shfl_xor(s, 2);
        s += __shfl_xor(s, 4); s += __shfl_xor(s, 8); s += __shfl_xor(s, 16);
        float mu = s * 0.0078125f;
        float t, d;
        t = v.x - mu; d = t * t;  t = v.y - mu; d += t * t;
        t = v.z - mu; d += t * t; t = v.w - mu; d += t * t;
        d += __shfl_xor(d, 1); d += __shfl_xor(d, 2);
        d += __shfl_xor(d, 4); d += __shfl_xor(d, 8); d += __shfl_xor(d, 16);
        float rs = rsqrtf(d * 0.0078125f + 1e-5f);
        v.x = (v.x - mu) * rs * gA.x + beA.x; v.y = (v.y - mu) * rs * gA.y + beA.y;
        v.z = (v.z - mu) * rs * gA.z + beA.z; v.w = (v.w - mu) * rs * gA.w + beA.w;
      }
      *(ushort4*)&out[grow + c] = make_ushort4(f2bf(v.x), f2bf(v.y), f2bf(v.z), f2bf(v.w));
    }
  }
}

// ---------------- pooling ----------------
__global__ __launch_bounds__(128) void pool_sum_kernel(const ushort* __restrict__ h,
                                                       const int* __restrict__ gid,
                                                       float* __restrict__ sums) {
  int f = threadIdx.x;
  int chunk = N_AA / gridDim.x;
  int start = blockIdx.x * chunk, end = start + chunk;
  int g = gid[start];
  float acc = 0.f;
  for (int i = start; i < end; ++i) {
    int gi = gid[i];
    if (gi != g) { atomicAdd(&sums[g * H + f], acc); acc = 0.f; g = gi; }
    acc += bf2f(h[(size_t)i * H + f]);
  }
  atomicAdd(&sums[g * H + f], acc);
}

__global__ void pool_final_kernel(const float* __restrict__ sums, const int* __restrict__ counts,
                                  float* __restrict__ out) {
  int b = blockIdx.x, f = threadIdx.x;
  float c = (float)counts[b];
  out[b * H + f] = sums[b * H + f] / fmaxf(c, 1.f);
  if (f == 0) out[B_GR * H + b] = c;
}

// ---------------- launch helpers ----------------
template<int K, bool ACT, bool SKIP_IN, bool SKIP_BUF, bool LN>
static void launch_gemm(const void* A, int nrows, const float* W, const float* bias,
                        const float* gamma, const float* beta, const ushort* skip,
                        ushort* out, hipStream_t stream) {
  int ntiles = nrows / 128;
  gemm_fused<K, ACT, SKIP_IN, SKIP_BUF, LN><<<ntiles, 512, 0, stream>>>(
      A, ntiles, W, bias, gamma, beta, skip, out);
}

template<bool ACT, bool SKIP, bool LN>
static void launch_mfma(const ushort* A, int nrows, const ushort* Wt, const float* bias,
                        const float* gamma, const float* beta, const ushort* skip,
                        ushort* out, hipStream_t stream) {
  int ngrp = nrows / 64;
  int grid = ngrp < 1024 ? ngrp : 1024;
  gemm_mfma<ACT, SKIP, LN><<<grid, 256, 0, stream>>>(
      A, ngrp, Wt, bias, gamma, beta, skip, out);
}

extern "C" void kernel_launch(void* const* d_in, const int* in_sizes, int n_in,
                              void* d_out, int out_size, void* d_ws, size_t ws_size,
                              hipStream_t stream) {
  (void)in_sizes; (void)n_in; (void)out_size; (void)ws_size;
  const float* h_aa0 = (const float*)d_in[0];
  const float* h_cg0 = (const float*)d_in[1];
  const int* src_cc = (const int*)d_in[2];
  const int* dst_cc = (const int*)d_in[3];
  const int* src_ca = (const int*)d_in[4];
  const int* dst_ca = (const int*)d_in[5];
  // d_in[6], d_in[7] (src_ac/dst_ac): dead in the reference — outputs depend only on h_aa
  const int* graph_id = (const int*)d_in[8];
  const float* W_cg0 = (const float*)d_in[9];
  const float* b_cg0 = (const float*)d_in[10];
  const float* g_cg0 = (const float*)d_in[11];
  const float* be_cg0 = (const float*)d_in[12];
  const float* W_aa0 = (const float*)d_in[13];
  const float* b_aa0 = (const float*)d_in[14];
  const float* g_aa0 = (const float*)d_in[15];
  const float* be_aa0 = (const float*)d_in[16];
  const float* W_cc = (const float*)d_in[17];
  const float* b_cc = (const float*)d_in[18];
  const float* W_m1 = (const float*)d_in[19];
  const float* b_m1 = (const float*)d_in[20];
  const float* g_m1 = (const float*)d_in[21];
  const float* be_m1 = (const float*)d_in[22];
  const float* W_ca = (const float*)d_in[23];
  const float* b_ca = (const float*)d_in[24];
  const float* W_m2 = (const float*)d_in[25];
  const float* b_m2 = (const float*)d_in[26];
  const float* g_m2 = (const float*)d_in[27];
  const float* be_m2 = (const float*)d_in[28];
  // d_in[29], d_in[30] (W_ac/b_ac): dead
  const float* W_f = (const float*)d_in[31];
  const float* b_f = (const float*)d_in[32];
  const float* g_f = (const float*)d_in[33];
  const float* be_f = (const float*)d_in[34];

  char* ws = (char*)d_ws;
  size_t off = 0;
  auto alloc = [&](size_t bytes) -> void* {
    void* p = ws + off;
    off = (off + bytes + 255) & ~(size_t)255;
    return p;
  };
  // node-feature buffers in bf16 (storage only; math fp32/MFMA-fp32-acc)
  ushort* cgA = (ushort*)alloc((size_t)N_CG * H * 2);
  ushort* G   = (ushort*)alloc((size_t)N_CG * H * 2);
  ushort* Hb  = (ushort*)alloc((size_t)N_AA * H * 2);
  ushort* AGG = (ushort*)alloc((size_t)N_AA * H * 2);
  int* cnt_s_cc = (int*)alloc((size_t)N_CG * 4);  // contiguous block for one memset
  int* cnt_d_cc = (int*)alloc((size_t)N_CG * 4);
  int* cnt_s_ca = (int*)alloc((size_t)N_CG * 4);
  int* cnt_d_ca = (int*)alloc((size_t)N_AA * 4);
  float* dout_cc = (float*)alloc((size_t)N_CG * 4);
  float* din_cc  = (float*)alloc((size_t)N_CG * 4);
  float* dout_ca = (float*)alloc((size_t)N_CG * 4);
  float* din_ca  = (float*)alloc((size_t)N_AA * 4);
  int* offs_cc = (int*)alloc((size_t)N_CG * 4);
  int* cur_cc  = (int*)alloc((size_t)N_CG * 4);
  int* offs_ca = (int*)alloc((size_t)N_AA * 4);
  int* cur_ca  = (int*)alloc((size_t)N_AA * 4);
  int* sorted_cc = (int*)alloc((size_t)E_CC * 4);
  int* sorted_ca = (int*)alloc((size_t)E_CA * 4);
  int* bsumA = (int*)alloc(1024);
  int* bsumB = (int*)alloc(1024);
  float* sums = (float*)alloc((size_t)B_GR * H * 4);
  int* counts = (int*)alloc(256);
  ushort* Wt_cc = (ushort*)alloc(H * H * 2);
  ushort* Wt_m1 = (ushort*)alloc(H * H * 2);
  ushort* Wt_ca = (ushort*)alloc(H * H * 2);
  ushort* Wt_m2 = (ushort*)alloc(H * H * 2);
  ushort* Wt_f  = (ushort*)alloc(H * H * 2);

  // zero the atomically-accumulated arrays
  hipMemsetAsync(cnt_s_cc, 0, (size_t)(3 * N_CG + N_AA) * 4, stream);
  hipMemsetAsync(sums, 0, (size_t)B_GR * H * 4, stream);

  // weight transposes (bf16), degrees, per-graph counts
  transpose_w_kernel<<<64, 256, 0, stream>>>(W_cc, Wt_cc);
  transpose_w_kernel<<<64, 256, 0, stream>>>(W_m1, Wt_m1);
  transpose_w_kernel<<<64, 256, 0, stream>>>(W_ca, Wt_ca);
  transpose_w_kernel<<<64, 256, 0, stream>>>(W_m2, Wt_m2);
  transpose_w_kernel<<<64, 256, 0, stream>>>(W_f, Wt_f);
  hist_kernel<<<1024, 256, 0, stream>>>(src_cc, E_CC, cnt_s_cc);
  hist_kernel<<<1024, 256, 0, stream>>>(dst_cc, E_CC, cnt_d_cc);
  hist_kernel<<<1024, 256, 0, stream>>>(src_ca, E_CA, cnt_s_ca);
  hist_kernel<<<1024, 256, 0, stream>>>(dst_ca, E_CA, cnt_d_ca);
  graph_count_kernel<<<1, 64, 0, stream>>>(graph_id, N_AA, counts);
  deg_kernel<<<256, 256, 0, stream>>>(cnt_s_cc, N_CG, dout_cc);
  deg_kernel<<<256, 256, 0, stream>>>(cnt_d_cc, N_CG, din_cc);
  deg_kernel<<<256, 256, 0, stream>>>(cnt_s_ca, N_CG, dout_ca);
  deg_kernel<<<1024, 256, 0, stream>>>(cnt_d_ca, N_AA, din_ca);

  // CSR by dst: cc
  scan1_kernel<<<N_CG / 1024, 256, 0, stream>>>(cnt_d_cc, offs_cc, bsumA);
  scan2_kernel<<<1, 256, 0, stream>>>(bsumA, N_CG / 1024);
  scan3_kernel<<<256, 256, 0, stream>>>(offs_cc, bsumA, N_CG, cur_cc);
  place_kernel<<<1024, 256, 0, stream>>>(src_cc, dst_cc, E_CC, cur_cc, sorted_cc);
  // CSR by dst: ca
  scan1_kernel<<<N_AA / 1024, 256, 0, stream>>>(cnt_d_ca, offs_ca, bsumB);
  scan2_kernel<<<1, 256, 0, stream>>>(bsumB, N_AA / 1024);
  scan3_kernel<<<256, 256, 0, stream>>>(offs_ca, bsumB, N_AA, cur_ca);
  place_kernel<<<1024, 256, 0, stream>>>(src_ca, dst_ca, E_CA, cur_ca, sorted_ca);

  // input MLPs (small K, VALU path)
  launch_gemm<32, true, false, false, true>(h_cg0, N_CG, W_cg0, b_cg0, g_cg0, be_cg0, nullptr, cgA, stream);
  launch_gemm<16, true, false, false, true>(h_aa0, N_AA, W_aa0, b_aa0, g_aa0, be_aa0, nullptr, Hb, stream);

  // cg_to_cg conv: gather + MFMA GEMM(+ELU) + skip(cgA), in-place on G
  gather_kernel<<<N_CG / 8, 256, 0, stream>>>(cgA, sorted_cc, offs_cc, cnt_d_cc, dout_cc, din_cc, G, N_CG);
  launch_mfma<true, true, false>(G, N_CG, Wt_cc, b_cc, nullptr, nullptr, cgA, G, stream);

  // m1 on aa (skip + LN), in-place on Hb
  launch_mfma<true, true, true>(Hb, N_AA, Wt_m1, b_m1, g_m1, be_m1, Hb, Hb, stream);

  // cg_to_aa conv: gather from G, MFMA GEMM(+ELU) + skip(Hb), in-place on AGG
  gather_kernel<<<N_AA / 8, 256, 0, stream>>>(G, sorted_ca, offs_ca, cnt_d_ca, dout_ca, din_ca, AGG, N_AA);
  launch_mfma<true, true, false>(AGG, N_AA, Wt_ca, b_ca, nullptr, nullptr, Hb, AGG, stream);

  // m2 (skip + LN), in-place
  launch_mfma<true, true, true>(AGG, N_AA, Wt_m2, b_m2, g_m2, be_m2, AGG, AGG, stream);

  // final layer (no act, no skip, LN), in-place
  launch_mfma<false, false, true>(AGG, N_AA, Wt_f, b_f, g_f, be_f, nullptr, AGG, stream);

  // mean pool per graph
  pool_sum_kernel<<<1024, 128, 0, stream>>>(AGG, graph_id, sums);
  pool_final_kernel<<<B_GR, 128, 0, stream>>>(sums, counts, (float*)d_out);
}

// Round 5
// 539.185 us; speedup vs baseline: 5.1832x; 1.3654x over previous
//
#include <hip/hip_runtime.h>

using ushort = unsigned short;

#define DEVFN static __device__ __forceinline__

constexpr int H = 128;
constexpr int N_AA = 262144, N_CG = 65536;
constexpr int E_CC = 262144, E_CA = 524288;
constexpr int B_GR = 64;

typedef __attribute__((ext_vector_type(8))) short bf16x8;
typedef __attribute__((ext_vector_type(4))) float f32x4;

DEVFN float elu(float x) { return x > 0.f ? x : __expf(x) - 1.f; }

DEVFN float bf2f(ushort s) { return __uint_as_float(((unsigned)s) << 16); }
DEVFN ushort f2bf(float f) {
  unsigned u = __float_as_uint(f);
  return (ushort)((u + 0x7FFFu + ((u >> 16) & 1u)) >> 16);
}

DEVFN void fma4(float4& c, float a, float4 w) {
  c.x += a * w.x; c.y += a * w.y; c.z += a * w.z; c.w += a * w.w;
}

// ================= graph prep =================
__global__ void hist_kernel(const int* __restrict__ idx, int n, int* __restrict__ cnt) {
  int i = blockIdx.x * blockDim.x + threadIdx.x;
  int stride = gridDim.x * blockDim.x;
  for (; i < n; i += stride) atomicAdd(&cnt[idx[i]], 1);
}

// graph_id is SORTED -> per-graph counts via binary-search boundaries (no atomics)
__global__ void graph_count_kernel(const int* __restrict__ gid, int n, int* __restrict__ counts) {
  int b = threadIdx.x;  // 64 threads, one per graph
  auto lb = [&](int v) {
    int lo = 0, hi = n;
    while (lo < hi) { int m = (lo + hi) >> 1; if (gid[m] < v) lo = m + 1; else hi = m; }
    return lo;
  };
  int s = lb(b), e = lb(b + 1);
  counts[b] = e - s;
}

__global__ void deg_kernel(const int* __restrict__ cnt, int n, float* __restrict__ d) {
  int i = blockIdx.x * blockDim.x + threadIdx.x;
  int stride = gridDim.x * blockDim.x;
  for (; i < n; i += stride) {
    int c = cnt[i]; if (c < 1) c = 1;
    d[i] = rsqrtf((float)c);
  }
}

// W [k=128][n=128] fp32 -> pre-swizzled transposed bf16 for LDS staging:
// Wsw[r*128 + j] = bf16(W[k][r]) with k = (j - (r&15)*8) & 127, so a ds_read at
// byte r*256 + ((ks*64+q*16+(r&15)*16)&255) yields Wt[r][ks*32+q*8 .. +8).
__global__ void wswz_kernel(const float* __restrict__ W, ushort* __restrict__ Wsw) {
  int idx = blockIdx.x * 256 + threadIdx.x;  // 64 x 256 = 16384
  int r = idx >> 7, j = idx & 127;
  int k = (j - ((r & 15) << 3)) & 127;
  Wsw[idx] = f2bf(W[k * 128 + r]);
}

// W_aa0 [k=16][n=128] fp32 -> padded transposed bf16 [n=128][k=32]
__global__ void wpad_kernel(const float* __restrict__ W, ushort* __restrict__ Wp) {
  int idx = blockIdx.x * 256 + threadIdx.x;  // 16 x 256 = 4096
  int n = idx >> 5, k = idx & 31;
  Wp[idx] = (k < 16) ? f2bf(W[k * 128 + n]) : (ushort)0;
}

// exclusive scan: 1024 elems / block (256 thr x int4)
__global__ void scan1_kernel(const int* __restrict__ in, int* __restrict__ out, int* __restrict__ bsum) {
  __shared__ int l[256];
  int tid = threadIdx.x;
  int base = blockIdx.x * 1024 + tid * 4;
  int4 v = *(const int4*)&in[base];
  int s = v.x + v.y + v.z + v.w;
  l[tid] = s; __syncthreads();
  for (int off = 1; off < 256; off <<= 1) {
    int t = (tid >= off) ? l[tid - off] : 0;
    __syncthreads();
    if (tid >= off) l[tid] += t;
    __syncthreads();
  }
  int excl = l[tid] - s;
  if (tid == 255) bsum[blockIdx.x] = l[255];
  int4 o; o.x = excl; o.y = o.x + v.x; o.z = o.y + v.y; o.w = o.z + v.z;
  *(int4*)&out[base] = o;
}

__global__ void scan2_kernel(int* __restrict__ bsum, int nb) {
  __shared__ int l[256];
  int tid = threadIdx.x;
  int v = (tid < nb) ? bsum[tid] : 0;
  l[tid] = v; __syncthreads();
  for (int off = 1; off < 256; off <<= 1) {
    int t = (tid >= off) ? l[tid - off] : 0;
    __syncthreads();
    if (tid >= off) l[tid] += t;
    __syncthreads();
  }
  if (tid < nb) bsum[tid] = l[tid] - v;
}

__global__ void scan3_kernel(int* __restrict__ offs, const int* __restrict__ bsum, int n, int* __restrict__ cur) {
  int i = blockIdx.x * blockDim.x + threadIdx.x;
  int stride = gridDim.x * blockDim.x;
  for (; i < n; i += stride) {
    int o = offs[i] + bsum[i >> 10];
    offs[i] = o; cur[i] = o;
  }
}

__global__ void place_kernel(const int* __restrict__ src, const int* __restrict__ dst, int E,
                             int* __restrict__ cur, int* __restrict__ sorted) {
  int i = blockIdx.x * blockDim.x + threadIdx.x;
  int stride = gridDim.x * blockDim.x;
  for (; i < E; i += stride) {
    int d = dst[i];
    int slot = atomicAdd(&cur[d], 1);
    sorted[slot] = src[i];
  }
}

// ================= CSR gather: out[d] = d_in[d] * sum_e d_out[src]*h[src] =================
__global__ __launch_bounds__(256) void gather_kernel(
    const ushort* __restrict__ h, const int* __restrict__ sorted_src,
    const int* __restrict__ offs, const int* __restrict__ cnt,
    const float* __restrict__ dout, const float* __restrict__ din,
    ushort* __restrict__ out, int ndst) {
  int lane = threadIdx.x & 31;
  int g0 = (blockIdx.x * blockDim.x + threadIdx.x) >> 5;
  int gstride = (gridDim.x * blockDim.x) >> 5;
  for (int d = g0; d < ndst; d += gstride) {
    int o = offs[d], c = cnt[d];
    float ax = 0.f, ay = 0.f, az = 0.f, aw = 0.f;
    for (int e = o; e < o + c; ++e) {
      int s = sorted_src[e];
      float w = dout[s];
      ushort4 u = *(const ushort4*)&h[(size_t)s * H + lane * 4];
      ax += w * bf2f(u.x); ay += w * bf2f(u.y);
      az += w * bf2f(u.z); aw += w * bf2f(u.w);
    }
    float di = din[d];
    ushort4 r = make_ushort4(f2bf(ax * di), f2bf(ay * di), f2bf(az * di), f2bf(aw * di));
    *(ushort4*)&out[(size_t)d * H + lane * 4] = r;
  }
}

// ================= MFMA building blocks =================
// All per-wave, 16 nodes/group. D layout (mfma_f32_16x16x32_bf16, m89-verified):
// lane(t=lane&15, q=lane>>4) owns node t, features nf*16 + q*4 + {0..3}.
// B-frag: lane(t,q) holds node t features [ks*32 + q*8, +8).

DEVFN void stage_w(const ushort* __restrict__ g, ushort* l, int tid, int nthr) {
  for (int i = tid; i < 2048; i += nthr)  // 32 KB
    *((uint4*)l + i) = *((const uint4*)g + i);
}

DEVFN void load_bfrag(const ushort* __restrict__ A, size_t mrow, int q, bf16x8 bfr[4]) {
#pragma unroll
  for (int ks = 0; ks < 4; ks++)
    bfr[ks] = *(const bf16x8*)(A + mrow + ks * 32 + q * 8);
}

// swizzled-LDS 128x128 GEMM accumulate (32 MFMA)
DEVFN void gemm128_lds(const ushort* __restrict__ Wlds, const bf16x8 bfr[4], f32x4 acc[8], int t, int q) {
#pragma unroll
  for (int ks = 0; ks < 4; ks++) {
    int coff = (ks * 64 + q * 16 + t * 16) & 255;  // byte offset in 256-B row (rot by t)
#pragma unroll
    for (int nf = 0; nf < 8; nf++) {
      bf16x8 wv = *(const bf16x8*)((const char*)Wlds + (nf * 16 + t) * 256 + coff);
      acc[nf] = __builtin_amdgcn_mfma_f32_16x16x32_bf16(wv, bfr[ks], acc[nf], 0, 0, 0);
    }
  }
}

// chain C (registers) -> wave-private LDS (bf16, t-rotated) -> next B-frag
DEVFN void chain_write(ushort* cb, int t, int q, const f32x4 a[8]) {
  asm volatile("s_waitcnt lgkmcnt(0)" ::: "memory");  // prior chain reads done
#pragma unroll
  for (int nf = 0; nf < 8; nf++) {
    int off = t * 256 + ((nf * 32 + q * 8 + t * 16) & 255);
    *(ushort4*)((char*)cb + off) =
        make_ushort4(f2bf(a[nf][0]), f2bf(a[nf][1]), f2bf(a[nf][2]), f2bf(a[nf][3]));
  }
}
DEVFN void chain_read(const ushort* cb, int t, int q, bf16x8 bfr[4]) {
#pragma unroll
  for (int ks = 0; ks < 4; ks++) {
    int off = t * 256 + ((ks * 64 + q * 16 + t * 16) & 255);
    bfr[ks] = *(const bf16x8*)((const char*)cb + off);
  }
}

template<bool ACT>
DEVFN void bias_act(f32x4 a[8], const float* __restrict__ bias, int q) {
#pragma unroll
  for (int nf = 0; nf < 8; nf++) {
    float4 bb = *(const float4*)&bias[nf * 16 + q * 4];
    a[nf][0] += bb.x; a[nf][1] += bb.y; a[nf][2] += bb.z; a[nf][3] += bb.w;
    if constexpr (ACT) {
#pragma unroll
      for (int e = 0; e < 4; e++) a[nf][e] = elu(a[nf][e]);
    }
  }
}

DEVFN void add_reg(f32x4 a[8], const f32x4 b[8]) {
#pragma unroll
  for (int nf = 0; nf < 8; nf++) {
#pragma unroll
    for (int e = 0; e < 4; e++) a[nf][e] += b[nf][e];
  }
}

DEVFN void add_skip_g(f32x4 a[8], const ushort* __restrict__ skip, size_t mrow, int q) {
#pragma unroll
  for (int nf = 0; nf < 8; nf++) {
    ushort4 u = *(const ushort4*)&skip[mrow + nf * 16 + q * 4];
    a[nf][0] += bf2f(u.x); a[nf][1] += bf2f(u.y); a[nf][2] += bf2f(u.z); a[nf][3] += bf2f(u.w);
  }
}

DEVFN void layernorm(f32x4 a[8], const float* __restrict__ gamma, const float* __restrict__ beta, int q) {
  float s = 0.f;
#pragma unroll
  for (int nf = 0; nf < 8; nf++) s += a[nf][0] + a[nf][1] + a[nf][2] + a[nf][3];
  s += __shfl_xor(s, 16); s += __shfl_xor(s, 32);
  float mu = s * 0.0078125f;
  float d = 0.f;
#pragma unroll
  for (int nf = 0; nf < 8; nf++) {
#pragma unroll
    for (int e = 0; e < 4; e++) { float x = a[nf][e] - mu; d += x * x; }
  }
  d += __shfl_xor(d, 16); d += __shfl_xor(d, 32);
  float rs = rsqrtf(d * 0.0078125f + 1e-5f);
#pragma unroll
  for (int nf = 0; nf < 8; nf++) {
    float4 gg = *(const float4*)&gamma[nf * 16 + q * 4];
    float4 be = *(const float4*)&beta[nf * 16 + q * 4];
    a[nf][0] = (a[nf][0] - mu) * rs * gg.x + be.x;
    a[nf][1] = (a[nf][1] - mu) * rs * gg.y + be.y;
    a[nf][2] = (a[nf][2] - mu) * rs * gg.z + be.z;
    a[nf][3] = (a[nf][3] - mu) * rs * gg.w + be.w;
  }
}

DEVFN void store_row(ushort* __restrict__ out, size_t mrow, const f32x4 a[8], int q) {
#pragma unroll
  for (int nf = 0; nf < 8; nf++)
    *(ushort4*)&out[mrow + nf * 16 + q * 4] =
        make_ushort4(f2bf(a[nf][0]), f2bf(a[nf][1]), f2bf(a[nf][2]), f2bf(a[nf][3]));
}

// ================= fused kernels =================
// input MLP aa (K=16 padded to 32) + LN, chained into m1 (elu, reg-skip, LN) -> Hb
__global__ __launch_bounds__(512) void fused_aa_kernel(
    const float* __restrict__ h0, int ngrp,
    const ushort* __restrict__ Wp,
    const float* __restrict__ b0, const float* __restrict__ g0, const float* __restrict__ be0,
    const ushort* __restrict__ Wswm1,
    const float* __restrict__ b1, const float* __restrict__ g1, const float* __restrict__ be1,
    ushort* __restrict__ out) {
  __shared__ ushort Wm1[16384];
  __shared__ ushort chain[8 * 2048 / 2];  // 8 waves x 16 nodes x 128 bf16 = 32 KB
  int tid = threadIdx.x;
  stage_w(Wswm1, Wm1, tid, 512);
  int lane = tid & 63, wave = tid >> 6;
  int t = lane & 15, q = lane >> 4;
  ushort* cb = chain + wave * 2048;
  bf16x8 wfa[8];
#pragma unroll
  for (int nf = 0; nf < 8; nf++)
    wfa[nf] = *(const bf16x8*)(Wp + (nf * 16 + t) * 32 + q * 8);
  __syncthreads();

  for (int grp = blockIdx.x; grp < ngrp; grp += gridDim.x) {
    int m0 = grp * 128 + wave * 16;
    size_t mrow = (size_t)(m0 + t) * H;
    bf16x8 bf0;
    if (q < 2) {
      const float* src = h0 + ((size_t)(m0 + t) << 4) + (q << 3);
      float4 u0 = *(const float4*)src;
      float4 u1 = *(const float4*)(src + 4);
      bf0[0] = (short)f2bf(u0.x); bf0[1] = (short)f2bf(u0.y);
      bf0[2] = (short)f2bf(u0.z); bf0[3] = (short)f2bf(u0.w);
      bf0[4] = (short)f2bf(u1.x); bf0[5] = (short)f2bf(u1.y);
      bf0[6] = (short)f2bf(u1.z); bf0[7] = (short)f2bf(u1.w);
    } else {
#pragma unroll
      for (int e = 0; e < 8; e++) bf0[e] = 0;
    }
    f32x4 a0[8];
#pragma unroll
    for (int nf = 0; nf < 8; nf++) a0[nf] = (f32x4){0.f, 0.f, 0.f, 0.f};
#pragma unroll
    for (int nf = 0; nf < 8; nf++)
      a0[nf] = __builtin_amdgcn_mfma_f32_16x16x32_bf16(wfa[nf], bf0, a0[nf], 0, 0, 0);
    bias_act<true>(a0, b0, q);
    layernorm(a0, g0, be0, q);

    bf16x8 bfr[4];
    chain_write(cb, t, q, a0);
    chain_read(cb, t, q, bfr);
    f32x4 a1[8];
#pragma unroll
    for (int nf = 0; nf < 8; nf++) a1[nf] = (f32x4){0.f, 0.f, 0.f, 0.f};
    gemm128_lds(Wm1, bfr, a1, t, q);
    bias_act<true>(a1, b1, q);
    add_reg(a1, a0);
    layernorm(a1, g1, be1, q);
    store_row(out, mrow, a1, q);
  }
}

// single GEMM + elu + global skip (cc layer)
__global__ __launch_bounds__(512) void cc_gemm_kernel(
    const ushort* __restrict__ A, int ngrp,
    const ushort* __restrict__ Wsw, const float* __restrict__ bias,
    const ushort* __restrict__ skip, ushort* __restrict__ out) {
  __shared__ ushort Wl[16384];
  int tid = threadIdx.x;
  stage_w(Wsw, Wl, tid, 512);
  int lane = tid & 63, wave = tid >> 6;
  int t = lane & 15, q = lane >> 4;
  __syncthreads();
  for (int grp = blockIdx.x; grp < ngrp; grp += gridDim.x) {
    int m0 = grp * 128 + wave * 16;
    size_t mrow = (size_t)(m0 + t) * H;
    bf16x8 bfr[4];
    load_bfrag(A, mrow, q, bfr);
    f32x4 a[8];
#pragma unroll
    for (int nf = 0; nf < 8; nf++) a[nf] = (f32x4){0.f, 0.f, 0.f, 0.f};
    gemm128_lds(Wl, bfr, a, t, q);
    bias_act<true>(a, bias, q);
    add_skip_g(a, skip, mrow, q);
    store_row(out, mrow, a, q);
  }
}

// ca GEMM (elu, +Hb skip) -> m2 (elu, reg-skip, LN) -> final (LN) -> out
__global__ __launch_bounds__(512) void fused3_kernel(
    const ushort* __restrict__ A, const ushort* __restrict__ Hbskip, int ngrp,
    const ushort* __restrict__ Wswca, const float* __restrict__ bca,
    const ushort* __restrict__ Wswm2, const float* __restrict__ bm2,
    const float* __restrict__ gm2, const float* __restrict__ bem2,
    const ushort* __restrict__ Wswf, const float* __restrict__ bf,
    const float* __restrict__ gf, const float* __restrict__ bef,
    ushort* __restrict__ out) {
  __shared__ ushort Wca[16384], Wm2[16384], Wf[16384];
  __shared__ ushort chain[8 * 2048 / 2];
  int tid = threadIdx.x;
  stage_w(Wswca, Wca, tid, 512);
  stage_w(Wswm2, Wm2, tid, 512);
  stage_w(Wswf, Wf, tid, 512);
  int lane = tid & 63, wave = tid >> 6;
  int t = lane & 15, q = lane >> 4;
  ushort* cb = chain + wave * 2048;
  __syncthreads();

  for (int grp = blockIdx.x; grp < ngrp; grp += gridDim.x) {
    int m0 = grp * 128 + wave * 16;
    size_t mrow = (size_t)(m0 + t) * H;
    bf16x8 bfr[4];
    load_bfrag(A, mrow, q, bfr);
    f32x4 a1[8];
#pragma unroll
    for (int nf = 0; nf < 8; nf++) a1[nf] = (f32x4){0.f, 0.f, 0.f, 0.f};
    gemm128_lds(Wca, bfr, a1, t, q);
    bias_act<true>(a1, bca, q);
    add_skip_g(a1, Hbskip, mrow, q);

    chain_write(cb, t, q, a1);
    chain_read(cb, t, q, bfr);
    f32x4 a2[8];
#pragma unroll
    for (int nf = 0; nf < 8; nf++) a2[nf] = (f32x4){0.f, 0.f, 0.f, 0.f};
    gemm128_lds(Wm2, bfr, a2, t, q);
    bias_act<true>(a2, bm2, q);
    add_reg(a2, a1);
    layernorm(a2, gm2, bem2, q);

    chain_write(cb, t, q, a2);
    chain_read(cb, t, q, bfr);
    f32x4 a3[8];
#pragma unroll
    for (int nf = 0; nf < 8; nf++) a3[nf] = (f32x4){0.f, 0.f, 0.f, 0.f};
    gemm128_lds(Wf, bfr, a3, t, q);
    bias_act<false>(a3, bf, q);
    layernorm(a3, gf, bef, q);
    store_row(out, mrow, a3, q);
  }
}

// ================= VALU GEMM for the cg input MLP (K=32, fp32 in) =================
template<int K, bool ACT, bool SKIP_IN, bool SKIP_BUF, bool LN>
__global__ __launch_bounds__(512) void gemm_fused(
    const void* __restrict__ Av, int ntiles,
    const float* __restrict__ W, const float* __restrict__ bias,
    const float* __restrict__ gamma, const float* __restrict__ beta,
    const ushort* __restrict__ skip, ushort* __restrict__ out) {
  constexpr int AS = K + 4;
  constexpr int KM = K - 1;
  constexpr int F4R = K / 4;
  __shared__ float Wl[K * H];
  __shared__ float Al[128 * AS];
  int tid = threadIdx.x;

  for (int q = tid; q < K * H / 4; q += 512)
    *(float4*)&Wl[q * 4] = *(const float4*)&W[q * 4];

  int tc = tid & 31, tr = tid >> 5;
  const int rot = (4 * tr) & KM;
  const int c = 4 * tc;
  const float* aBase = Al + (tr * 8) * AS;

  for (int tile = blockIdx.x; tile < ntiles; tile += gridDim.x) {
    int r0 = tile * 128;
    __syncthreads();
    for (int q = tid; q < 128 * F4R; q += 512) {
      int r = q / F4R, cc = (q % F4R) * 4;
      float4 v = *(const float4*)((const float*)Av + (size_t)(r0 + r) * K + cc);
      int rr = (4 * (r >> 3)) & KM;
      *(float4*)&Al[r * AS + ((cc + rr) & KM)] = v;
    }
    __syncthreads();

    float4 acc[8];
#pragma unroll
    for (int i = 0; i < 8; i++) acc[i] = make_float4(0.f, 0.f, 0.f, 0.f);

#pragma unroll 2
    for (int k = 0; k < K; k += 4) {
      int kp = (k + rot) & KM;
      float4 av[8];
#pragma unroll
      for (int r8 = 0; r8 < 8; r8++) av[r8] = *(const float4*)(aBase + r8 * AS + kp);
      float4 w0 = *(const float4*)&Wl[(k + 0) * H + c];
      float4 w1 = *(const float4*)&Wl[(k + 1) * H + c];
      float4 w2 = *(const float4*)&Wl[(k + 2) * H + c];
      float4 w3 = *(const float4*)&Wl[(k + 3) * H + c];
#pragma unroll
      for (int r8 = 0; r8 < 8; r8++) {
        float4 a = av[r8];
        fma4(acc[r8], a.x, w0); fma4(acc[r8], a.y, w1);
        fma4(acc[r8], a.z, w2); fma4(acc[r8], a.w, w3);
      }
    }

    float4 bA = *(const float4*)&bias[c];
    float4 gA, beA;
    if constexpr (LN) {
      gA = *(const float4*)&gamma[c];
      beA = *(const float4*)&beta[c];
    }
#pragma unroll
    for (int r8 = 0; r8 < 8; r8++) {
      int r = tr * 8 + r8;
      size_t grow = (size_t)(r0 + r) * H;
      float4 v;
      v.x = acc[r8].x + bA.x; v.y = acc[r8].y + bA.y;
      v.z = acc[r8].z + bA.z; v.w = acc[r8].w + bA.w;
      if constexpr (ACT) {
        v.x = elu(v.x); v.y = elu(v.y); v.z = elu(v.z); v.w = elu(v.w);
      }
      if constexpr (SKIP_IN) {
        float4 sA = *(const float4*)&Al[r * AS + ((c + rot) & KM)];
        v.x += sA.x; v.y += sA.y; v.z += sA.z; v.w += sA.w;
      }
      if constexpr (SKIP_BUF) {
        ushort4 u = *(const ushort4*)&skip[grow + c];
        v.x += bf2f(u.x); v.y += bf2f(u.y); v.z += bf2f(u.z); v.w += bf2f(u.w);
      }
      if constexpr (LN) {
        float s = v.x + v.y + v.z + v.w;
        s += __shfl_xor(s, 1); s += __shfl_xor(s, 2);
        s += __shfl_xor(s, 4); s += __shfl_xor(s, 8); s += __shfl_xor(s, 16);
        float mu = s * 0.0078125f;
        float t, d;
        t = v.x - mu; d = t * t;  t = v.y - mu; d += t * t;
        t = v.z - mu; d += t * t; t = v.w - mu; d += t * t;
        d += __shfl_xor(d, 1); d += __shfl_xor(d, 2);
        d += __shfl_xor(d, 4); d += __shfl_xor(d, 8); d += __shfl_xor(d, 16);
        float rs = rsqrtf(d * 0.0078125f + 1e-5f);
        v.x = (v.x - mu) * rs * gA.x + beA.x; v.y = (v.y - mu) * rs * gA.y + beA.y;
        v.z = (v.z - mu) * rs * gA.z + beA.z; v.w = (v.w - mu) * rs * gA.w + beA.w;
      }
      *(ushort4*)&out[grow + c] = make_ushort4(f2bf(v.x), f2bf(v.y), f2bf(v.z), f2bf(v.w));
    }
  }
}

// ================= pooling =================
__global__ __launch_bounds__(128) void pool_sum_kernel(const ushort* __restrict__ h,
                                                       const int* __restrict__ gid,
                                                       float* __restrict__ sums) {
  int f = threadIdx.x;
  int chunk = N_AA / gridDim.x;
  int start = blockIdx.x * chunk, end = start + chunk;
  int g = gid[start];
  float acc = 0.f;
  for (int i = start; i < end; ++i) {
    int gi = gid[i];
    if (gi != g) { atomicAdd(&sums[g * H + f], acc); acc = 0.f; g = gi; }
    acc += bf2f(h[(size_t)i * H + f]);
  }
  atomicAdd(&sums[g * H + f], acc);
}

__global__ void pool_final_kernel(const float* __restrict__ sums, const int* __restrict__ counts,
                                  float* __restrict__ out) {
  int b = blockIdx.x, f = threadIdx.x;
  float c = (float)counts[b];
  out[b * H + f] = sums[b * H + f] / fmaxf(c, 1.f);
  if (f == 0) out[B_GR * H + b] = c;
}

// ================= launch =================
extern "C" void kernel_launch(void* const* d_in, const int* in_sizes, int n_in,
                              void* d_out, int out_size, void* d_ws, size_t ws_size,
                              hipStream_t stream) {
  (void)in_sizes; (void)n_in; (void)out_size; (void)ws_size;
  const float* h_aa0 = (const float*)d_in[0];
  const float* h_cg0 = (const float*)d_in[1];
  const int* src_cc = (const int*)d_in[2];
  const int* dst_cc = (const int*)d_in[3];
  const int* src_ca = (const int*)d_in[4];
  const int* dst_ca = (const int*)d_in[5];
  // d_in[6], d_in[7] (src_ac/dst_ac): dead in the reference — outputs depend only on h_aa
  const int* graph_id = (const int*)d_in[8];
  const float* W_cg0 = (const float*)d_in[9];
  const float* b_cg0 = (const float*)d_in[10];
  const float* g_cg0 = (const float*)d_in[11];
  const float* be_cg0 = (const float*)d_in[12];
  const float* W_aa0 = (const float*)d_in[13];
  const float* b_aa0 = (const float*)d_in[14];
  const float* g_aa0 = (const float*)d_in[15];
  const float* be_aa0 = (const float*)d_in[16];
  const float* W_cc = (const float*)d_in[17];
  const float* b_cc = (const float*)d_in[18];
  const float* W_m1 = (const float*)d_in[19];
  const float* b_m1 = (const float*)d_in[20];
  const float* g_m1 = (const float*)d_in[21];
  const float* be_m1 = (const float*)d_in[22];
  const float* W_ca = (const float*)d_in[23];
  const float* b_ca = (const float*)d_in[24];
  const float* W_m2 = (const float*)d_in[25];
  const float* b_m2 = (const float*)d_in[26];
  const float* g_m2 = (const float*)d_in[27];
  const float* be_m2 = (const float*)d_in[28];
  // d_in[29], d_in[30] (W_ac/b_ac): dead
  const float* W_f = (const float*)d_in[31];
  const float* b_f = (const float*)d_in[32];
  const float* g_f = (const float*)d_in[33];
  const float* be_f = (const float*)d_in[34];

  char* ws = (char*)d_ws;
  size_t off = 0;
  auto alloc = [&](size_t bytes) -> void* {
    void* p = ws + off;
    off = (off + bytes + 255) & ~(size_t)255;
    return p;
  };
  ushort* cgA = (ushort*)alloc((size_t)N_CG * H * 2);
  ushort* G   = (ushort*)alloc((size_t)N_CG * H * 2);
  ushort* Hb  = (ushort*)alloc((size_t)N_AA * H * 2);
  ushort* AGG = (ushort*)alloc((size_t)N_AA * H * 2);
  int* cnt_s_cc = (int*)alloc((size_t)N_CG * 4);  // contiguous block for one memset
  int* cnt_d_cc = (int*)alloc((size_t)N_CG * 4);
  int* cnt_s_ca = (int*)alloc((size_t)N_CG * 4);
  int* cnt_d_ca = (int*)alloc((size_t)N_AA * 4);
  float* dout_cc = (float*)alloc((size_t)N_CG * 4);
  float* din_cc  = (float*)alloc((size_t)N_CG * 4);
  float* dout_ca = (float*)alloc((size_t)N_CG * 4);
  float* din_ca  = (float*)alloc((size_t)N_AA * 4);
  int* offs_cc = (int*)alloc((size_t)N_CG * 4);
  int* cur_cc  = (int*)alloc((size_t)N_CG * 4);
  int* offs_ca = (int*)alloc((size_t)N_AA * 4);
  int* cur_ca  = (int*)alloc((size_t)N_AA * 4);
  int* sorted_cc = (int*)alloc((size_t)E_CC * 4);
  int* sorted_ca = (int*)alloc((size_t)E_CA * 4);
  int* bsumA = (int*)alloc(1024);
  int* bsumB = (int*)alloc(1024);
  float* sums = (float*)alloc((size_t)B_GR * H * 4);
  int* counts = (int*)alloc(256);
  ushort* Wsw_cc = (ushort*)alloc(H * H * 2);
  ushort* Wsw_m1 = (ushort*)alloc(H * H * 2);
  ushort* Wsw_ca = (ushort*)alloc(H * H * 2);
  ushort* Wsw_m2 = (ushort*)alloc(H * H * 2);
  ushort* Wsw_f  = (ushort*)alloc(H * H * 2);
  ushort* Wp_aa  = (ushort*)alloc(H * 32 * 2);

  hipMemsetAsync(cnt_s_cc, 0, (size_t)(3 * N_CG + N_AA) * 4, stream);
  hipMemsetAsync(sums, 0, (size_t)B_GR * H * 4, stream);

  // weight prep (transpose + swizzle / pad), degrees, per-graph counts
  wswz_kernel<<<64, 256, 0, stream>>>(W_cc, Wsw_cc);
  wswz_kernel<<<64, 256, 0, stream>>>(W_m1, Wsw_m1);
  wswz_kernel<<<64, 256, 0, stream>>>(W_ca, Wsw_ca);
  wswz_kernel<<<64, 256, 0, stream>>>(W_m2, Wsw_m2);
  wswz_kernel<<<64, 256, 0, stream>>>(W_f, Wsw_f);
  wpad_kernel<<<16, 256, 0, stream>>>(W_aa0, Wp_aa);
  hist_kernel<<<1024, 256, 0, stream>>>(src_cc, E_CC, cnt_s_cc);
  hist_kernel<<<1024, 256, 0, stream>>>(dst_cc, E_CC, cnt_d_cc);
  hist_kernel<<<1024, 256, 0, stream>>>(src_ca, E_CA, cnt_s_ca);
  hist_kernel<<<1024, 256, 0, stream>>>(dst_ca, E_CA, cnt_d_ca);
  graph_count_kernel<<<1, 64, 0, stream>>>(graph_id, N_AA, counts);
  deg_kernel<<<256, 256, 0, stream>>>(cnt_s_cc, N_CG, dout_cc);
  deg_kernel<<<256, 256, 0, stream>>>(cnt_d_cc, N_CG, din_cc);
  deg_kernel<<<256, 256, 0, stream>>>(cnt_s_ca, N_CG, dout_ca);
  deg_kernel<<<1024, 256, 0, stream>>>(cnt_d_ca, N_AA, din_ca);

  // CSR by dst: cc
  scan1_kernel<<<N_CG / 1024, 256, 0, stream>>>(cnt_d_cc, offs_cc, bsumA);
  scan2_kernel<<<1, 256, 0, stream>>>(bsumA, N_CG / 1024);
  scan3_kernel<<<256, 256, 0, stream>>>(offs_cc, bsumA, N_CG, cur_cc);
  place_kernel<<<1024, 256, 0, stream>>>(src_cc, dst_cc, E_CC, cur_cc, sorted_cc);
  // CSR by dst: ca
  scan1_kernel<<<N_AA / 1024, 256, 0, stream>>>(cnt_d_ca, offs_ca, bsumB);
  scan2_kernel<<<1, 256, 0, stream>>>(bsumB, N_AA / 1024);
  scan3_kernel<<<256, 256, 0, stream>>>(offs_ca, bsumB, N_AA, cur_ca);
  place_kernel<<<1024, 256, 0, stream>>>(src_ca, dst_ca, E_CA, cur_ca, sorted_ca);

  // cg input MLP (VALU, fp32 in)
  gemm_fused<32, true, false, false, true><<<N_CG / 128, 512, 0, stream>>>(
      h_cg0, N_CG / 128, W_cg0, b_cg0, g_cg0, be_cg0, nullptr, cgA);

  // aa input MLP + m1 fused -> Hb
  fused_aa_kernel<<<N_AA / 128, 512, 0, stream>>>(
      h_aa0, N_AA / 128, Wp_aa, b_aa0, g_aa0, be_aa0,
      Wsw_m1, b_m1, g_m1, be_m1, Hb);

  // cg_to_cg conv: gather + GEMM(+elu) + skip(cgA), in-place on G
  gather_kernel<<<N_CG / 8, 256, 0, stream>>>(cgA, sorted_cc, offs_cc, cnt_d_cc, dout_cc, din_cc, G, N_CG);
  cc_gemm_kernel<<<N_CG / 128, 512, 0, stream>>>(G, N_CG / 128, Wsw_cc, b_cc, cgA, G);

  // cg_to_aa gather -> AGG, then fused ca+m2+final in-place on AGG
  gather_kernel<<<N_AA / 8, 256, 0, stream>>>(G, sorted_ca, offs_ca, cnt_d_ca, dout_ca, din_ca, AGG, N_AA);
  fused3_kernel<<<N_AA / 128, 512, 0, stream>>>(
      AGG, Hb, N_AA / 128,
      Wsw_ca, b_ca, Wsw_m2, b_m2, g_m2, be_m2,
      Wsw_f, b_f, g_f, be_f, AGG);

  // mean pool per graph
  pool_sum_kernel<<<1024, 128, 0, stream>>>(AGG, graph_id, sums);
  pool_final_kernel<<<B_GR, 128, 0, stream>>>(sums, counts, (float*)d_out);
}